// Round 22
// baseline (262.719 us; speedup 1.0000x reference)
//
#include <hip/hip_runtime.h>
#include <hip/hip_bf16.h>

typedef __bf16 bf16;
typedef bf16 bf16x8 __attribute__((ext_vector_type(8)));
typedef float f32x4 __attribute__((ext_vector_type(4)));

#define MFMA16(a, b, c) __builtin_amdgcn_mfma_f32_16x16x32_bf16((a), (b), (c), 0, 0, 0)

// Problem constants
#define MM 3
#define AA 4
#define BB 2048
#define LL 7
#define HH 256
#define VN 50000

__device__ __forceinline__ float ftanh(float x) {
    float e = __expf(2.f * x);
    float r = __builtin_amdgcn_rcpf(e + 1.f);
    return 1.f - 2.f * r;
}
__device__ __forceinline__ float bf2f(unsigned u) {
    union { unsigned u; float f; } x; x.u = u << 16; return x.f;
}
__device__ __forceinline__ unsigned f2bf(float f) {
    bf16 b = (bf16)f;
    return (unsigned)__builtin_bit_cast(unsigned short, b);
}

// ---------------------------------------------------------------------------
// prep: transposed bf16 weights, cos/sin edge tables, zero S accumulator
// ---------------------------------------------------------------------------
__global__ void prep_kernel(const float* __restrict__ scale_W, const float* __restrict__ attn_W,
                            const float* __restrict__ inter_W, const float* __restrict__ out_W,
                            const float* __restrict__ edge_emb,
                            bf16* __restrict__ scale_WT, bf16* __restrict__ WtopT,
                            bf16* __restrict__ WbotT, bf16* __restrict__ inter_WT,
                            bf16* __restrict__ out_WT,
                            float* __restrict__ ce, float* __restrict__ se,
                            float* __restrict__ S) {
    int idx = blockIdx.x * blockDim.x + threadIdx.x;
    int stride = gridDim.x * blockDim.x;
    for (int i = idx; i < 256 * 256; i += stride) {
        int k = i >> 8, c = i & 255;
        scale_WT[c * 256 + k] = (bf16)scale_W[i];
    }
    for (int i = idx; i < 512 * 256; i += stride) {
        int c = i >> 8, k = i & 255;
        WtopT[c * 256 + k] = (bf16)attn_W[k * 512 + c];
        WbotT[c * 256 + k] = (bf16)attn_W[(256 + k) * 512 + c];
    }
    for (int i = idx; i < 512 * 512; i += stride) {
        int k = i >> 9, c = i & 511;
        inter_WT[c * 512 + k] = (bf16)inter_W[i];
    }
    for (int i = idx; i < 512 * 256; i += stride) {
        int k = i >> 8, c = i & 255;
        out_WT[c * 512 + k] = (bf16)out_W[i];
    }
    for (int i = idx; i < 16 * 128; i += stride) {
        float e = edge_emb[i];
        ce[i] = cosf(e);
        se[i] = sinf(e);
    }
    for (int i = idx; i < 3 * 512; i += stride) S[i] = 0.f;
}

// ---------------------------------------------------------------------------
// K1: scaled_emb[v] = node_emb[v] @ scale_W + scale_b  — 64-row W-in-regs
// ---------------------------------------------------------------------------
__global__ __launch_bounds__(512, 4) void emb_gemm_kernel(
    const float* __restrict__ node_emb, const bf16* __restrict__ scale_WT,
    const float* __restrict__ scale_b, bf16* __restrict__ scaled_emb) {
    extern __shared__ char smem[];
    bf16* Al = (bf16*)smem;  // [64][264] = 33792 B
    const int tid = threadIdx.x;
    const int vb = blockIdx.x * 64;
    const int w = tid >> 6, l = tid & 63, lr = l & 15, g = l >> 4;

    bf16x8 wf[8][2];
#pragma unroll
    for (int ks = 0; ks < 8; ++ks)
#pragma unroll
        for (int ct = 0; ct < 2; ++ct)
            wf[ks][ct] = *(const bf16x8*)(scale_WT + (size_t)(w * 32 + ct * 16 + lr) * 256 +
                                          ks * 32 + g * 8);
    float bia[2];
#pragma unroll
    for (int ct = 0; ct < 2; ++ct) bia[ct] = scale_b[w * 32 + ct * 16 + lr];

    for (int it = 0; it < 8; ++it) {
        int i = tid + it * 512;
        int r = i >> 6, kq = i & 63;
        int v = vb + r;
        float4 x = (v < VN) ? *(const float4*)(node_emb + (size_t)v * 256 + kq * 4)
                            : make_float4(0.f, 0.f, 0.f, 0.f);
        bf16* d = Al + r * 264 + kq * 4;
        d[0] = (bf16)x.x; d[1] = (bf16)x.y; d[2] = (bf16)x.z; d[3] = (bf16)x.w;
    }
    __syncthreads();

    for (int rt = 0; rt < 4; ++rt) {
        f32x4 acc[2] = {};
#pragma unroll
        for (int ks = 0; ks < 8; ++ks) {
            bf16x8 aF = *(const bf16x8*)(Al + (rt * 16 + lr) * 264 + ks * 32 + g * 8);
#pragma unroll
            for (int ct = 0; ct < 2; ++ct) acc[ct] = MFMA16(aF, wf[ks][ct], acc[ct]);
        }
#pragma unroll
        for (int ct = 0; ct < 2; ++ct) {
            int col = w * 32 + ct * 16 + lr;
#pragma unroll
            for (int i2 = 0; i2 < 4; ++i2) {
                int v = vb + rt * 16 + g * 4 + i2;
                if (v < VN) scaled_emb[(size_t)v * 256 + col] = (bf16)(acc[ct][i2] + bia[ct]);
            }
        }
    }
}

// ---------------------------------------------------------------------------
// A: gather + rotational scan, global->global. 1 wave per path instance n.
// scanned[n_l][p][256] bf16, linear. No LDS, no barriers, tiny regs.
// ---------------------------------------------------------------------------
__global__ __launch_bounds__(256) void scan_kernel(
    const int* __restrict__ tokens, const int* __restrict__ etok,
    const bf16* __restrict__ scaled_emb, const float* __restrict__ ce,
    const float* __restrict__ se, bf16* __restrict__ scanned, int m0) {
    const int tid = threadIdx.x;
    const int n_l = blockIdx.x * 4 + (tid >> 6);
    const int cp = tid & 63, c0 = cp * 2;
    const int b = n_l & 2047, a = (n_l >> 11) & 3, mrel = n_l >> 13;
    const int base = ((m0 + mrel) * AA + a) * BB + b;
    const int* tk = tokens + (base << 3);
    const int* eb = etok + base * LL;
    bf16* orow = scanned + (size_t)n_l * 2048;

    unsigned x0r = *(const unsigned*)(scaled_emb + (size_t)tk[0] * 256 + c0);
    unsigned x0i = *(const unsigned*)(scaled_emb + (size_t)tk[0] * 256 + c0 + 128);
    *(unsigned*)(orow + c0) = x0r;
    *(unsigned*)(orow + c0 + 128) = x0i;
    float Sr0 = bf2f(x0r & 0xffffu), Sr1 = bf2f(x0r >> 16);
    float Si0 = bf2f(x0i & 0xffffu), Si1 = bf2f(x0i >> 16);
    float P0r = 1.f, P0i = 0.f, P1r = 1.f, P1i = 0.f;
#pragma unroll
    for (int k = 1; k <= LL; ++k) {
        int e = eb[k - 1];
        int v = tk[k];
        float2 crv = *(const float2*)(ce + e * 128 + c0);
        float2 civ = *(const float2*)(se + e * 128 + c0);
        float t0r = P0r * crv.x - P0i * civ.x, t0i = P0r * civ.x + P0i * crv.x;
        float t1r = P1r * crv.y - P1i * civ.y, t1i = P1r * civ.y + P1i * crv.y;
        P0r = t0r; P0i = t0i; P1r = t1r; P1i = t1i;
        unsigned xr = *(const unsigned*)(scaled_emb + (size_t)v * 256 + c0);
        unsigned xi = *(const unsigned*)(scaled_emb + (size_t)v * 256 + c0 + 128);
        float xr0 = bf2f(xr & 0xffffu), xr1 = bf2f(xr >> 16);
        float xi0 = bf2f(xi & 0xffffu), xi1 = bf2f(xi >> 16);
        Sr0 += P0r * xr0 - P0i * xi0; Si0 += P0r * xi0 + P0i * xr0;
        Sr1 += P1r * xr1 - P1i * xi1; Si1 += P1r * xi1 + P1i * xr1;
        float inv = 1.f / (float)(k + 1);
        *(unsigned*)(orow + k * 256 + c0) = f2bf(Sr0 * inv) | (f2bf(Sr1 * inv) << 16);
        *(unsigned*)(orow + k * 256 + c0 + 128) = f2bf(Si0 * inv) | (f2bf(Si1 * inv) << 16);
    }
}

// ---------------------------------------------------------------------------
// B: attn GEMM + logits + softmax + fused wsum/relu/a-reduce -> hid.
// 1024 thr / 16 waves, 16 n = (4a x 4b), same LDS (78.6 KB) -> 2 blocks/CU =
// 32 waves/CU (2x r21 occupancy, same work: 16 cols x 2 cc passes per wave).
// Logit partials: waves w and w+8 atomicAdd into lg2 slot w&7 (zero-inited).
// ---------------------------------------------------------------------------
__global__ __launch_bounds__(1024, 4) void attn_kernel(
    const bf16* __restrict__ scanned, const bf16* __restrict__ WtopT,
    const bf16* __restrict__ WbotT, const float* __restrict__ attn_b,
    const float* __restrict__ ctx, float* __restrict__ hid, int m0) {
    extern __shared__ char smem[];
    bf16* Als = (bf16*)smem;               // 128*256*2 = 65536
    bf16* h0l = (bf16*)(smem + 65536);     // 16*264*2  =  8448
    float* lg2 = (float*)(smem + 73984);   // 128*9*4   =  4608 -> 78592
    const int tid = threadIdx.x;
    const int w = tid >> 6, l = tid & 63, lr = l & 15, g = l >> 4;
    const int bg = blockIdx.x;
    const int mrel = bg >> 9;              // 512 b-groups per m
    const int b0 = (bg & 511) * 4;
    const int m = m0 + mrel;

    // zero logit accumulators (atomicAdd targets)
    for (int i = tid; i < 1152; i += 1024) lg2[i] = 0.f;

    // stage 64KB: rows = q*8+p, q = a*4+bi (4a x 4b). swizzle chunk^p; h0l pad.
    for (int it = 0; it < 4; ++it) {
        int i = tid + it * 1024;       // 16B-chunk index 0..4095
        int row = i >> 5, Lch = i & 31;
        int q = row >> 3, p = row & 7;
        int a = q >> 2, bi = q & 3;
        const bf16* rp = scanned + ((size_t)(mrel * AA + a) * BB + b0 + bi) * 2048 + p * 256;
        bf16x8 x = *(const bf16x8*)(rp + Lch * 8);
        int pch = (Lch & 24) | ((Lch & 7) ^ p);
        *(bf16x8*)(Als + row * 256 + pch * 8) = x;
        if (p == 0) *(bf16x8*)(h0l + q * 264 + Lch * 8) = x;
    }
    __syncthreads();

    const int bsel = g >> 1;
    float pv[8][4] = {};
#pragma unroll 1
    for (int cc = 0; cc < 2; ++cc) {
        const int cb = cc * 256 + w * 16;
        // y0 = h0 . Wtop for 16 n's — A from padded h0l (conflict-free)
        f32x4 a0 = {};
        {
            bf16x8 wt[8];
#pragma unroll
            for (int ks = 0; ks < 8; ++ks)
                wt[ks] = *(const bf16x8*)(WtopT + (size_t)(cb + lr) * 256 + ks * 32 + g * 8);
#pragma unroll
            for (int ks = 0; ks < 8; ++ks) {
                bf16x8 aF = *(const bf16x8*)(h0l + lr * 264 + ks * 32 + g * 8);
                a0 = MFMA16(aF, wt[ks], a0);
            }
        }
        // broadcast y0[q][lane's col] from producer lanes (static reg indices)
        float y0sel[8];
#pragma unroll
        for (int rt = 0; rt < 8; ++rt) {
            float t0 = __shfl(a0[(2 * rt) & 3], (((2 * rt) >> 2) << 4) + lr, 64);
            float t1 = __shfl(a0[(2 * rt + 1) & 3], (((2 * rt + 1) >> 2) << 4) + lr, 64);
            y0sel[rt] = bsel ? t1 : t0;
        }
        bf16x8 wb[8];
#pragma unroll
        for (int ks = 0; ks < 8; ++ks)
            wb[ks] = *(const bf16x8*)(WbotT + (size_t)(cb + lr) * 256 + ks * 32 + g * 8);
        float bia = attn_b[cb + lr];
        float cxv = ctx[cb + lr];
#pragma unroll
        for (int rt = 0; rt < 8; ++rt) {
            float y0v = y0sel[rt];
            f32x4 accE, accO;
            accE[0] = y0v; accE[1] = y0v; accE[2] = y0v; accE[3] = y0v;
            accO[0] = 0.f; accO[1] = 0.f; accO[2] = 0.f; accO[3] = 0.f;
            __builtin_amdgcn_s_setprio(1);
#pragma unroll
            for (int ks = 0; ks < 4; ++ks) {
                bf16x8 aE = *(const bf16x8*)(Als + (rt * 16 + lr) * 256 +
                                             ((((2 * ks) * 4 + g) ^ (lr & 7)) << 3));
                bf16x8 aO = *(const bf16x8*)(Als + (rt * 16 + lr) * 256 +
                                             ((((2 * ks + 1) * 4 + g) ^ (lr & 7)) << 3));
                accE = MFMA16(aE, wb[2 * ks], accE);
                accO = MFMA16(aO, wb[2 * ks + 1], accO);
            }
            __builtin_amdgcn_s_setprio(0);
#pragma unroll
            for (int i2 = 0; i2 < 4; ++i2)
                pv[rt][i2] += cxv * ftanh(accE[i2] + accO[i2] + bia);
        }
        __builtin_amdgcn_sched_barrier(0);
    }
    // reduce logit partials over 16 column-lanes, then LDS atomic per slot
#pragma unroll
    for (int msk = 1; msk < 16; msk <<= 1)
#pragma unroll
        for (int rt = 0; rt < 8; ++rt)
#pragma unroll
            for (int i2 = 0; i2 < 4; ++i2) pv[rt][i2] += __shfl_xor(pv[rt][i2], msk, 64);
    if (lr == 0) {
#pragma unroll
        for (int rt = 0; rt < 8; ++rt)
#pragma unroll
            for (int i2 = 0; i2 < 4; ++i2) {
                int row = rt * 16 + g * 4 + i2;
                if (row & 7) atomicAdd(&lg2[row * 9 + (w & 7)], pv[rt][i2]);
            }
    }
    __syncthreads();

    // softmax per q (7 positions) -> weights in lg2 column 8
    if (tid < 16) {
        int q = tid;
        float lv[LL], mx = -1e30f;
#pragma unroll
        for (int j = 1; j <= LL; ++j) {
            float sv = 0.f;
#pragma unroll
            for (int w8 = 0; w8 < 8; ++w8) sv += lg2[(q * 8 + j) * 9 + w8];
            lv[j - 1] = sv;
            mx = fmaxf(mx, sv);
        }
        float ssum = 0.f, ev[LL];
#pragma unroll
        for (int j = 0; j < LL; ++j) { ev[j] = __expf(lv[j] - mx); ssum += ev[j]; }
        float inv = 1.f / ssum;
#pragma unroll
        for (int j = 0; j < LL; ++j) lg2[(q * 8 + j + 1) * 9 + 8] = ev[j] * inv;
    }
    __syncthreads();

    // fused epilogue: hid[b0+bi][m][c] = sum_a relu([h0 | sum_j w_j h_j])
    {
        int item = tid;                // 0..1023 = 4 bi x 256 c-pairs
        int bi = item >> 8, cp = item & 255;
        int c0 = cp * 2;
        float acc0 = 0.f, acc1 = 0.f;
        if (c0 < 256) {
#pragma unroll
            for (int a = 0; a < AA; ++a) {
                int q = a * 4 + bi;
                unsigned u = *(const unsigned*)(Als + q * 2048 + c0);  // p=0 row, key 0
                acc0 += fmaxf(0.f, bf2f(u & 0xffffu));
                acc1 += fmaxf(0.f, bf2f(u >> 16));
            }
        } else {
            int cb2 = c0 - 256;
            int ch = cb2 >> 3, of = cb2 & 7;
#pragma unroll
            for (int a = 0; a < AA; ++a) {
                int q = a * 4 + bi;
                float s0 = 0.f, s1 = 0.f;
#pragma unroll
                for (int j = 1; j <= LL; ++j) {
                    unsigned u = *(const unsigned*)(Als + (q * 8 + j) * 256 +
                                                    ((ch ^ j) << 3) + of);
                    float wj = lg2[(q * 8 + j) * 9 + 8];
                    s0 += wj * bf2f(u & 0xffffu);
                    s1 += wj * bf2f(u >> 16);
                }
                acc0 += fmaxf(0.f, s0);
                acc1 += fmaxf(0.f, s1);
            }
        }
        float2 o; o.x = acc0; o.y = acc1;
        *(float2*)(hid + ((size_t)(b0 + bi) * 3 + m) * 512 + c0) = o;
    }
}

// ---------------------------------------------------------------------------
// K4a: S[m][c] += sum_b tanh(hid[b][m] . inter_W[:,c] + inter_b[c])
// ---------------------------------------------------------------------------
__global__ __launch_bounds__(1024, 4) void inter_kernel(
    const float* __restrict__ hid, const bf16* __restrict__ inter_WT,
    const float* __restrict__ inter_b, float* __restrict__ S) {
    extern __shared__ char smem[];
    bf16* Al = (bf16*)smem;  // [32][520] = 33280 B
    const int tid = threadIdx.x;
    const int m = blockIdx.y, rb = blockIdx.x * 32;
    const int w = tid >> 6, l = tid & 63, lr = l & 15, g = l >> 4;
    for (int it = 0; it < 4; ++it) {
        int i = tid + it * 1024;
        int r = i >> 7, kq = i & 127;
        float4 x = *(const float4*)(hid + ((size_t)(rb + r) * 3 + m) * 512 + kq * 4);
        bf16* d = Al + r * 520 + kq * 4;
        d[0] = (bf16)x.x; d[1] = (bf16)x.y; d[2] = (bf16)x.z; d[3] = (bf16)x.w;
    }
    __syncthreads();
#pragma unroll 1
    for (int cc = 0; cc < 2; ++cc) {
        int c = cc * 256 + w * 16 + lr;
        bf16x8 wf[16];
#pragma unroll
        for (int ks = 0; ks < 16; ++ks)
            wf[ks] = *(const bf16x8*)(inter_WT + (size_t)c * 512 + ks * 32 + g * 8);
        float biav = inter_b[c];
        float csum = 0.f;
        for (int rt = 0; rt < 2; ++rt) {
            f32x4 acc = {};
#pragma unroll
            for (int ks = 0; ks < 16; ++ks) {
                bf16x8 aF = *(const bf16x8*)(Al + (rt * 16 + lr) * 520 + ks * 32 + g * 8);
                acc = MFMA16(aF, wf[ks], acc);
            }
#pragma unroll
            for (int i2 = 0; i2 < 4; ++i2) csum += ftanh(acc[i2] + biav);
        }
        csum += __shfl_xor(csum, 16, 64);
        csum += __shfl_xor(csum, 32, 64);
        if (g == 0) atomicAdd(&S[m * 512 + c], csum);
        __builtin_amdgcn_sched_barrier(0);
    }
}

// ---------------------------------------------------------------------------
// K4b: scores[m] = (sum_c S[m][c] * inter_context[c]) / 2048
// ---------------------------------------------------------------------------
__global__ void scores_kernel(const float* __restrict__ S, const float* __restrict__ ictx2,
                              float* __restrict__ scores) {
    __shared__ float red[512];
    int t = threadIdx.x;
    for (int m = 0; m < 3; ++m) {
        red[t] = S[m * 512 + t] * ictx2[t];
        __syncthreads();
        for (int st = 256; st > 0; st >>= 1) {
            if (t < st) red[t] += red[t + st];
            __syncthreads();
        }
        if (t == 0) scores[m] = red[0] * (1.f / 2048.f);
        __syncthreads();
    }
}

// ---------------------------------------------------------------------------
// K4c: out[b] = (sum_m hid[b][m] * scores[m]) @ out_W + out_b
// ---------------------------------------------------------------------------
__global__ __launch_bounds__(1024, 4) void out_kernel(
    const float* __restrict__ hid, const float* __restrict__ scores,
    const bf16* __restrict__ out_WT, const float* __restrict__ out_b,
    float* __restrict__ out) {
    extern __shared__ char smem[];
    bf16* Al = (bf16*)smem;  // [32][520] = 33280 B
    const int tid = threadIdx.x;
    const int rb = blockIdx.x * 32;
    const int w = tid >> 6, l = tid & 63, lr = l & 15, g = l >> 4;
    float s0 = scores[0], s1 = scores[1], s2 = scores[2];
    for (int it = 0; it < 4; ++it) {
        int i = tid + it * 1024;
        int r = i >> 7, kq = i & 127;
        const float* hp = hid + (size_t)(rb + r) * 1536 + kq * 4;
        float4 x0 = *(const float4*)(hp);
        float4 x1 = *(const float4*)(hp + 512);
        float4 x2 = *(const float4*)(hp + 1024);
        bf16* d = Al + r * 520 + kq * 4;
        d[0] = (bf16)(x0.x * s0 + x1.x * s1 + x2.x * s2);
        d[1] = (bf16)(x0.y * s0 + x1.y * s1 + x2.y * s2);
        d[2] = (bf16)(x0.z * s0 + x1.z * s1 + x2.z * s2);
        d[3] = (bf16)(x0.w * s0 + x1.w * s1 + x2.w * s2);
    }
    __syncthreads();
    int c = w * 16 + lr;
    bf16x8 wf[16];
#pragma unroll
    for (int ks = 0; ks < 16; ++ks)
        wf[ks] = *(const bf16x8*)(out_WT + (size_t)c * 512 + ks * 32 + g * 8);
    float biav = out_b[c];
    for (int rt = 0; rt < 2; ++rt) {
        f32x4 acc = {};
#pragma unroll
        for (int ks = 0; ks < 16; ++ks) {
            bf16x8 aF = *(const bf16x8*)(Al + (rt * 16 + lr) * 520 + ks * 32 + g * 8);
            acc = MFMA16(aF, wf[ks], acc);
        }
#pragma unroll
        for (int i2 = 0; i2 < 4; ++i2)
            out[(size_t)(rb + rt * 16 + g * 4 + i2) * 256 + c] = acc[i2] + biav;
    }
}

// ---------------------------------------------------------------------------
extern "C" void kernel_launch(void* const* d_in, const int* in_sizes, int n_in,
                              void* d_out, int out_size, void* d_ws, size_t ws_size,
                              hipStream_t stream) {
    const int* tokens = (const int*)d_in[0];
    const int* etok = (const int*)d_in[1];
    const float* node_emb = (const float*)d_in[2];
    const float* edge_emb = (const float*)d_in[3];
    const float* scale_W = (const float*)d_in[4];
    const float* scale_b = (const float*)d_in[5];
    const float* attn_W = (const float*)d_in[6];
    const float* attn_b = (const float*)d_in[7];
    const float* ictx = (const float*)d_in[8];
    const float* inter_W = (const float*)d_in[9];
    const float* inter_b = (const float*)d_in[10];
    const float* ictx2 = (const float*)d_in[11];
    const float* out_W = (const float*)d_in[12];
    const float* out_b = (const float*)d_in[13];
    float* out = (float*)d_out;
    char* ws = (char*)d_ws;

    // ws layout (bytes)
    size_t off = 0;
    bf16* scale_WT = (bf16*)(ws + off); off += 256 * 256 * 2;            // 131072
    bf16* WtopT = (bf16*)(ws + off);    off += 512 * 256 * 2;            // 262144
    bf16* WbotT = (bf16*)(ws + off);    off += 512 * 256 * 2;            // 262144
    bf16* inter_WT = (bf16*)(ws + off); off += 512 * 512 * 2;            // 524288
    bf16* out_WT = (bf16*)(ws + off);   off += 512 * 256 * 2;            // 262144
    float* ce = (float*)(ws + off);     off += 16 * 128 * 4;             // 8192
    float* se = (float*)(ws + off);     off += 16 * 128 * 4;             // 8192
    float* S = (float*)(ws + off);      off += 3 * 512 * 4;              // 6144
    float* scores = (float*)(ws + off); off += 256;
    bf16* scaled_emb = (bf16*)(ws + off); off += (size_t)VN * 256 * 2;   // 25.6 MB
    float* hid = (float*)(ws + off);    off += (size_t)BB * 3 * 512 * 4; // 12.6 MB
    bf16* scanned = (bf16*)(ws + off);
    const size_t chunk_bytes = (size_t)8192 * 8 * 256 * 2;               // 33.55 MB
    size_t need3 = off + chunk_bytes;        // nm=1 (3 passes)
    size_t need1 = off + 3 * chunk_bytes;    // nm=3 (single pass)
    if (ws_size < need3) return;  // insufficient scratch -> fail loudly (zeros)
    const int nm = (ws_size >= need1) ? 3 : 1;

    const int lds_k1 = 64 * 264 * 2;   // 33792
    const int lds_B = 78592;           // Als + h0l + lg2
    const int lds_k4 = 32 * 520 * 2;   // 33280
    (void)hipFuncSetAttribute((const void*)attn_kernel,
                              hipFuncAttributeMaxDynamicSharedMemorySize, lds_B);

    prep_kernel<<<1024, 256, 0, stream>>>(scale_W, attn_W, inter_W, out_W, edge_emb,
                                          scale_WT, WtopT, WbotT, inter_WT, out_WT, ce, se, S);
    emb_gemm_kernel<<<(VN + 63) / 64, 512, lds_k1, stream>>>(node_emb, scale_WT, scale_b,
                                                             scaled_emb);
    for (int m0 = 0; m0 < 3; m0 += nm) {
        scan_kernel<<<nm * 2048, 256, 0, stream>>>(tokens, etok, scaled_emb, ce, se,
                                                   scanned, m0);
        attn_kernel<<<nm * 512, 1024, lds_B, stream>>>(scanned, WtopT, WbotT, attn_b, ictx,
                                                       hid, m0);
    }
    inter_kernel<<<dim3(BB / 32, MM), 1024, lds_k4, stream>>>(hid, inter_WT, inter_b, S);
    scores_kernel<<<1, 512, 0, stream>>>(S, ictx2, scores);
    out_kernel<<<BB / 32, 1024, lds_k4, stream>>>(hid, scores, out_WT, out_b, out);
}

// Round 23
// 218.294 us; speedup vs baseline: 1.2035x; 1.2035x over previous
//
#include <hip/hip_runtime.h>
#include <hip/hip_bf16.h>

typedef __bf16 bf16;
typedef bf16 bf16x8 __attribute__((ext_vector_type(8)));
typedef float f32x4 __attribute__((ext_vector_type(4)));

#define MFMA16(a, b, c) __builtin_amdgcn_mfma_f32_16x16x32_bf16((a), (b), (c), 0, 0, 0)

// Problem constants
#define MM 3
#define AA 4
#define BB 2048
#define LL 7
#define HH 256
#define VN 50000

__device__ __forceinline__ float ftanh(float x) {
    float e = __expf(2.f * x);
    float r = __builtin_amdgcn_rcpf(e + 1.f);
    return 1.f - 2.f * r;
}
__device__ __forceinline__ float bf2f(unsigned u) {
    union { unsigned u; float f; } x; x.u = u << 16; return x.f;
}
__device__ __forceinline__ unsigned f2bf(float f) {
    bf16 b = (bf16)f;
    return (unsigned)__builtin_bit_cast(unsigned short, b);
}

// ---------------------------------------------------------------------------
// prep: transposed bf16 weights, cos/sin edge tables, zero S accumulator
// ---------------------------------------------------------------------------
__global__ void prep_kernel(const float* __restrict__ scale_W, const float* __restrict__ attn_W,
                            const float* __restrict__ inter_W, const float* __restrict__ out_W,
                            const float* __restrict__ edge_emb,
                            bf16* __restrict__ scale_WT, bf16* __restrict__ WtopT,
                            bf16* __restrict__ WbotT, bf16* __restrict__ inter_WT,
                            bf16* __restrict__ out_WT,
                            float* __restrict__ ce, float* __restrict__ se,
                            float* __restrict__ S) {
    int idx = blockIdx.x * blockDim.x + threadIdx.x;
    int stride = gridDim.x * blockDim.x;
    for (int i = idx; i < 256 * 256; i += stride) {
        int k = i >> 8, c = i & 255;
        scale_WT[c * 256 + k] = (bf16)scale_W[i];
    }
    for (int i = idx; i < 512 * 256; i += stride) {
        int c = i >> 8, k = i & 255;
        WtopT[c * 256 + k] = (bf16)attn_W[k * 512 + c];
        WbotT[c * 256 + k] = (bf16)attn_W[(256 + k) * 512 + c];
    }
    for (int i = idx; i < 512 * 512; i += stride) {
        int k = i >> 9, c = i & 511;
        inter_WT[c * 512 + k] = (bf16)inter_W[i];
    }
    for (int i = idx; i < 512 * 256; i += stride) {
        int k = i >> 8, c = i & 255;
        out_WT[c * 512 + k] = (bf16)out_W[i];
    }
    for (int i = idx; i < 16 * 128; i += stride) {
        float e = edge_emb[i];
        ce[i] = cosf(e);
        se[i] = sinf(e);
    }
    for (int i = idx; i < 3 * 512; i += stride) S[i] = 0.f;
}

// ---------------------------------------------------------------------------
// K1: scaled_emb[v] = node_emb[v] @ scale_W + scale_b  — 64-row W-in-regs
// ---------------------------------------------------------------------------
__global__ __launch_bounds__(512, 4) void emb_gemm_kernel(
    const float* __restrict__ node_emb, const bf16* __restrict__ scale_WT,
    const float* __restrict__ scale_b, bf16* __restrict__ scaled_emb) {
    extern __shared__ char smem[];
    bf16* Al = (bf16*)smem;  // [64][264] = 33792 B
    const int tid = threadIdx.x;
    const int vb = blockIdx.x * 64;
    const int w = tid >> 6, l = tid & 63, lr = l & 15, g = l >> 4;

    bf16x8 wf[8][2];
#pragma unroll
    for (int ks = 0; ks < 8; ++ks)
#pragma unroll
        for (int ct = 0; ct < 2; ++ct)
            wf[ks][ct] = *(const bf16x8*)(scale_WT + (size_t)(w * 32 + ct * 16 + lr) * 256 +
                                          ks * 32 + g * 8);
    float bia[2];
#pragma unroll
    for (int ct = 0; ct < 2; ++ct) bia[ct] = scale_b[w * 32 + ct * 16 + lr];

    for (int it = 0; it < 8; ++it) {
        int i = tid + it * 512;
        int r = i >> 6, kq = i & 63;
        int v = vb + r;
        float4 x = (v < VN) ? *(const float4*)(node_emb + (size_t)v * 256 + kq * 4)
                            : make_float4(0.f, 0.f, 0.f, 0.f);
        bf16* d = Al + r * 264 + kq * 4;
        d[0] = (bf16)x.x; d[1] = (bf16)x.y; d[2] = (bf16)x.z; d[3] = (bf16)x.w;
    }
    __syncthreads();

    for (int rt = 0; rt < 4; ++rt) {
        f32x4 acc[2] = {};
#pragma unroll
        for (int ks = 0; ks < 8; ++ks) {
            bf16x8 aF = *(const bf16x8*)(Al + (rt * 16 + lr) * 264 + ks * 32 + g * 8);
#pragma unroll
            for (int ct = 0; ct < 2; ++ct) acc[ct] = MFMA16(aF, wf[ks][ct], acc[ct]);
        }
#pragma unroll
        for (int ct = 0; ct < 2; ++ct) {
            int col = w * 32 + ct * 16 + lr;
#pragma unroll
            for (int i2 = 0; i2 < 4; ++i2) {
                int v = vb + rt * 16 + g * 4 + i2;
                if (v < VN) scaled_emb[(size_t)v * 256 + col] = (bf16)(acc[ct][i2] + bia[ct]);
            }
        }
    }
}

// ---------------------------------------------------------------------------
// A: gather + rotational scan, global->global. 1 wave per path instance n.
// scanned[n_l][p][256] bf16, linear. No LDS, no barriers, tiny regs.
// ---------------------------------------------------------------------------
__global__ __launch_bounds__(256) void scan_kernel(
    const int* __restrict__ tokens, const int* __restrict__ etok,
    const bf16* __restrict__ scaled_emb, const float* __restrict__ ce,
    const float* __restrict__ se, bf16* __restrict__ scanned, int m0) {
    const int tid = threadIdx.x;
    const int n_l = blockIdx.x * 4 + (tid >> 6);
    const int cp = tid & 63, c0 = cp * 2;
    const int b = n_l & 2047, a = (n_l >> 11) & 3, mrel = n_l >> 13;
    const int base = ((m0 + mrel) * AA + a) * BB + b;
    const int* tk = tokens + (base << 3);
    const int* eb = etok + base * LL;
    bf16* orow = scanned + (size_t)n_l * 2048;

    unsigned x0r = *(const unsigned*)(scaled_emb + (size_t)tk[0] * 256 + c0);
    unsigned x0i = *(const unsigned*)(scaled_emb + (size_t)tk[0] * 256 + c0 + 128);
    *(unsigned*)(orow + c0) = x0r;
    *(unsigned*)(orow + c0 + 128) = x0i;
    float Sr0 = bf2f(x0r & 0xffffu), Sr1 = bf2f(x0r >> 16);
    float Si0 = bf2f(x0i & 0xffffu), Si1 = bf2f(x0i >> 16);
    float P0r = 1.f, P0i = 0.f, P1r = 1.f, P1i = 0.f;
#pragma unroll
    for (int k = 1; k <= LL; ++k) {
        int e = eb[k - 1];
        int v = tk[k];
        float2 crv = *(const float2*)(ce + e * 128 + c0);
        float2 civ = *(const float2*)(se + e * 128 + c0);
        float t0r = P0r * crv.x - P0i * civ.x, t0i = P0r * civ.x + P0i * crv.x;
        float t1r = P1r * crv.y - P1i * civ.y, t1i = P1r * civ.y + P1i * crv.y;
        P0r = t0r; P0i = t0i; P1r = t1r; P1i = t1i;
        unsigned xr = *(const unsigned*)(scaled_emb + (size_t)v * 256 + c0);
        unsigned xi = *(const unsigned*)(scaled_emb + (size_t)v * 256 + c0 + 128);
        float xr0 = bf2f(xr & 0xffffu), xr1 = bf2f(xr >> 16);
        float xi0 = bf2f(xi & 0xffffu), xi1 = bf2f(xi >> 16);
        Sr0 += P0r * xr0 - P0i * xi0; Si0 += P0r * xi0 + P0i * xr0;
        Sr1 += P1r * xr1 - P1i * xi1; Si1 += P1r * xi1 + P1i * xr1;
        float inv = 1.f / (float)(k + 1);
        *(unsigned*)(orow + k * 256 + c0) = f2bf(Sr0 * inv) | (f2bf(Sr1 * inv) << 16);
        *(unsigned*)(orow + k * 256 + c0 + 128) = f2bf(Si0 * inv) | (f2bf(Si1 * inv) << 16);
    }
}

// ---------------------------------------------------------------------------
// B: attn GEMM + logits + softmax + FUSED weighted-sum/relu/a-reduce -> hid.
// Block = 16 n = (4 a) x (4 b), same m -> full a-reduction in-block, plain
// stores to hid, wsum kernel and wsm buffer eliminated.
// r19 core otherwise: padded h0l (conflict-free y0), lr&7 chunk swizzle Y1.
// ---------------------------------------------------------------------------
__global__ __launch_bounds__(512, 4) void attn_kernel(
    const bf16* __restrict__ scanned, const bf16* __restrict__ WtopT,
    const bf16* __restrict__ WbotT, const float* __restrict__ attn_b,
    const float* __restrict__ ctx, float* __restrict__ hid, int m0) {
    extern __shared__ char smem[];
    bf16* Als = (bf16*)smem;               // 128*256*2 = 65536
    bf16* h0l = (bf16*)(smem + 65536);     // 16*264*2  =  8448
    float* lg2 = (float*)(smem + 73984);   // 128*9*4   =  4608 -> 78592
    const int tid = threadIdx.x;
    const int w = tid >> 6, l = tid & 63, lr = l & 15, g = l >> 4;
    const int bg = blockIdx.x;
    const int mrel = bg >> 9;              // 512 b-groups per m
    const int b0 = (bg & 511) * 4;
    const int m = m0 + mrel;

    // stage 64KB: rows = q*8+p, q = a*4+bi (4a x 4b). swizzle chunk^p; h0l pad.
    for (int it = 0; it < 8; ++it) {
        int i = tid + it * 512;        // 16B-chunk index 0..4095
        int row = i >> 5, Lch = i & 31;
        int q = row >> 3, p = row & 7;
        int a = q >> 2, bi = q & 3;
        const bf16* rp = scanned + ((size_t)(mrel * AA + a) * BB + b0 + bi) * 2048 + p * 256;
        bf16x8 x = *(const bf16x8*)(rp + Lch * 8);
        int pch = (Lch & 24) | ((Lch & 7) ^ p);
        *(bf16x8*)(Als + row * 256 + pch * 8) = x;
        if (p == 0) *(bf16x8*)(h0l + q * 264 + Lch * 8) = x;
    }
    __syncthreads();

    const int bsel = g >> 1;
    float pv[8][4] = {};
#pragma unroll 1
    for (int cc = 0; cc < 4; ++cc) {
        const int cb = cc * 128 + w * 16;
        // y0 = h0 . Wtop for 16 n's — A from padded h0l (conflict-free)
        f32x4 a0 = {};
        {
            bf16x8 wt[8];
#pragma unroll
            for (int ks = 0; ks < 8; ++ks)
                wt[ks] = *(const bf16x8*)(WtopT + (size_t)(cb + lr) * 256 + ks * 32 + g * 8);
#pragma unroll
            for (int ks = 0; ks < 8; ++ks) {
                bf16x8 aF = *(const bf16x8*)(h0l + lr * 264 + ks * 32 + g * 8);
                a0 = MFMA16(aF, wt[ks], a0);
            }
        }
        // broadcast y0[q][lane's col] from producer lanes (static reg indices)
        float y0sel[8];
#pragma unroll
        for (int rt = 0; rt < 8; ++rt) {
            float t0 = __shfl(a0[(2 * rt) & 3], (((2 * rt) >> 2) << 4) + lr, 64);
            float t1 = __shfl(a0[(2 * rt + 1) & 3], (((2 * rt + 1) >> 2) << 4) + lr, 64);
            y0sel[rt] = bsel ? t1 : t0;
        }
        bf16x8 wb[8];
#pragma unroll
        for (int ks = 0; ks < 8; ++ks)
            wb[ks] = *(const bf16x8*)(WbotT + (size_t)(cb + lr) * 256 + ks * 32 + g * 8);
        float bia = attn_b[cb + lr];
        float cxv = ctx[cb + lr];
#pragma unroll
        for (int rt = 0; rt < 8; ++rt) {
            float y0v = y0sel[rt];
            f32x4 accE, accO;
            accE[0] = y0v; accE[1] = y0v; accE[2] = y0v; accE[3] = y0v;
            accO[0] = 0.f; accO[1] = 0.f; accO[2] = 0.f; accO[3] = 0.f;
            __builtin_amdgcn_s_setprio(1);
#pragma unroll
            for (int ks = 0; ks < 4; ++ks) {
                bf16x8 aE = *(const bf16x8*)(Als + (rt * 16 + lr) * 256 +
                                             ((((2 * ks) * 4 + g) ^ (lr & 7)) << 3));
                bf16x8 aO = *(const bf16x8*)(Als + (rt * 16 + lr) * 256 +
                                             ((((2 * ks + 1) * 4 + g) ^ (lr & 7)) << 3));
                accE = MFMA16(aE, wb[2 * ks], accE);
                accO = MFMA16(aO, wb[2 * ks + 1], accO);
            }
            __builtin_amdgcn_s_setprio(0);
#pragma unroll
            for (int i2 = 0; i2 < 4; ++i2)
                pv[rt][i2] += cxv * ftanh(accE[i2] + accO[i2] + bia);
        }
        __builtin_amdgcn_sched_barrier(0);
    }
    // reduce logit partials over 16 column-lanes
#pragma unroll
    for (int msk = 1; msk < 16; msk <<= 1)
#pragma unroll
        for (int rt = 0; rt < 8; ++rt)
#pragma unroll
            for (int i2 = 0; i2 < 4; ++i2) pv[rt][i2] += __shfl_xor(pv[rt][i2], msk, 64);
    if (lr == 0) {
#pragma unroll
        for (int rt = 0; rt < 8; ++rt)
#pragma unroll
            for (int i2 = 0; i2 < 4; ++i2) {
                int row = rt * 16 + g * 4 + i2;
                if (row & 7) lg2[row * 9 + w] = pv[rt][i2];
            }
    }
    __syncthreads();

    // softmax per q (7 positions) -> weights in lg2 column 8
    if (tid < 16) {
        int q = tid;
        float lv[LL], mx = -1e30f;
#pragma unroll
        for (int j = 1; j <= LL; ++j) {
            float sv = 0.f;
#pragma unroll
            for (int w8 = 0; w8 < 8; ++w8) sv += lg2[(q * 8 + j) * 9 + w8];
            lv[j - 1] = sv;
            mx = fmaxf(mx, sv);
        }
        float ssum = 0.f, ev[LL];
#pragma unroll
        for (int j = 0; j < LL; ++j) { ev[j] = __expf(lv[j] - mx); ssum += ev[j]; }
        float inv = 1.f / ssum;
#pragma unroll
        for (int j = 0; j < LL; ++j) lg2[(q * 8 + j + 1) * 9 + 8] = ev[j] * inv;
    }
    __syncthreads();

    // fused epilogue: hid[b0+bi][m][c] = sum_a relu([h0 | sum_j w_j h_j])
    for (int it2 = 0; it2 < 2; ++it2) {
        int item = tid + it2 * 512;    // 0..1023 = 4 bi x 256 c-pairs
        int bi = item >> 8, cp = item & 255;
        int c0 = cp * 2;
        float acc0 = 0.f, acc1 = 0.f;
        if (c0 < 256) {
#pragma unroll
            for (int a = 0; a < AA; ++a) {
                int q = a * 4 + bi;
                unsigned u = *(const unsigned*)(Als + q * 2048 + c0);  // p=0 row, key 0
                acc0 += fmaxf(0.f, bf2f(u & 0xffffu));
                acc1 += fmaxf(0.f, bf2f(u >> 16));
            }
        } else {
            int cb2 = c0 - 256;
            int ch = cb2 >> 3, of = cb2 & 7;
#pragma unroll
            for (int a = 0; a < AA; ++a) {
                int q = a * 4 + bi;
                float s0 = 0.f, s1 = 0.f;
#pragma unroll
                for (int j = 1; j <= LL; ++j) {
                    unsigned u = *(const unsigned*)(Als + (q * 8 + j) * 256 +
                                                    ((ch ^ j) << 3) + of);
                    float wj = lg2[(q * 8 + j) * 9 + 8];
                    s0 += wj * bf2f(u & 0xffffu);
                    s1 += wj * bf2f(u >> 16);
                }
                acc0 += fmaxf(0.f, s0);
                acc1 += fmaxf(0.f, s1);
            }
        }
        float2 o; o.x = acc0; o.y = acc1;
        *(float2*)(hid + ((size_t)(b0 + bi) * 3 + m) * 512 + c0) = o;
    }
}

// ---------------------------------------------------------------------------
// K4a: S[m][c] += sum_b tanh(hid[b][m] . inter_W[:,c] + inter_b[c])
// ---------------------------------------------------------------------------
__global__ __launch_bounds__(1024, 4) void inter_kernel(
    const float* __restrict__ hid, const bf16* __restrict__ inter_WT,
    const float* __restrict__ inter_b, float* __restrict__ S) {
    extern __shared__ char smem[];
    bf16* Al = (bf16*)smem;  // [32][520] = 33280 B
    const int tid = threadIdx.x;
    const int m = blockIdx.y, rb = blockIdx.x * 32;
    const int w = tid >> 6, l = tid & 63, lr = l & 15, g = l >> 4;
    for (int it = 0; it < 4; ++it) {
        int i = tid + it * 1024;
        int r = i >> 7, kq = i & 127;
        float4 x = *(const float4*)(hid + ((size_t)(rb + r) * 3 + m) * 512 + kq * 4);
        bf16* d = Al + r * 520 + kq * 4;
        d[0] = (bf16)x.x; d[1] = (bf16)x.y; d[2] = (bf16)x.z; d[3] = (bf16)x.w;
    }
    __syncthreads();
#pragma unroll 1
    for (int cc = 0; cc < 2; ++cc) {
        int c = cc * 256 + w * 16 + lr;
        bf16x8 wf[16];
#pragma unroll
        for (int ks = 0; ks < 16; ++ks)
            wf[ks] = *(const bf16x8*)(inter_WT + (size_t)c * 512 + ks * 32 + g * 8);
        float biav = inter_b[c];
        float csum = 0.f;
        for (int rt = 0; rt < 2; ++rt) {
            f32x4 acc = {};
#pragma unroll
            for (int ks = 0; ks < 16; ++ks) {
                bf16x8 aF = *(const bf16x8*)(Al + (rt * 16 + lr) * 520 + ks * 32 + g * 8);
                acc = MFMA16(aF, wf[ks], acc);
            }
#pragma unroll
            for (int i2 = 0; i2 < 4; ++i2) csum += ftanh(acc[i2] + biav);
        }
        csum += __shfl_xor(csum, 16, 64);
        csum += __shfl_xor(csum, 32, 64);
        if (g == 0) atomicAdd(&S[m * 512 + c], csum);
        __builtin_amdgcn_sched_barrier(0);
    }
}

// ---------------------------------------------------------------------------
// K4b: scores[m] = (sum_c S[m][c] * inter_context[c]) / 2048
// ---------------------------------------------------------------------------
__global__ void scores_kernel(const float* __restrict__ S, const float* __restrict__ ictx2,
                              float* __restrict__ scores) {
    __shared__ float red[512];
    int t = threadIdx.x;
    for (int m = 0; m < 3; ++m) {
        red[t] = S[m * 512 + t] * ictx2[t];
        __syncthreads();
        for (int st = 256; st > 0; st >>= 1) {
            if (t < st) red[t] += red[t + st];
            __syncthreads();
        }
        if (t == 0) scores[m] = red[0] * (1.f / 2048.f);
        __syncthreads();
    }
}

// ---------------------------------------------------------------------------
// K4c: out[b] = (sum_m hid[b][m] * scores[m]) @ out_W + out_b
// ---------------------------------------------------------------------------
__global__ __launch_bounds__(1024, 4) void out_kernel(
    const float* __restrict__ hid, const float* __restrict__ scores,
    const bf16* __restrict__ out_WT, const float* __restrict__ out_b,
    float* __restrict__ out) {
    extern __shared__ char smem[];
    bf16* Al = (bf16*)smem;  // [32][520] = 33280 B
    const int tid = threadIdx.x;
    const int rb = blockIdx.x * 32;
    const int w = tid >> 6, l = tid & 63, lr = l & 15, g = l >> 4;
    float s0 = scores[0], s1 = scores[1], s2 = scores[2];
    for (int it = 0; it < 4; ++it) {
        int i = tid + it * 1024;
        int r = i >> 7, kq = i & 127;
        const float* hp = hid + (size_t)(rb + r) * 1536 + kq * 4;
        float4 x0 = *(const float4*)(hp);
        float4 x1 = *(const float4*)(hp + 512);
        float4 x2 = *(const float4*)(hp + 1024);
        bf16* d = Al + r * 520 + kq * 4;
        d[0] = (bf16)(x0.x * s0 + x1.x * s1 + x2.x * s2);
        d[1] = (bf16)(x0.y * s0 + x1.y * s1 + x2.y * s2);
        d[2] = (bf16)(x0.z * s0 + x1.z * s1 + x2.z * s2);
        d[3] = (bf16)(x0.w * s0 + x1.w * s1 + x2.w * s2);
    }
    __syncthreads();
    int c = w * 16 + lr;
    bf16x8 wf[16];
#pragma unroll
    for (int ks = 0; ks < 16; ++ks)
        wf[ks] = *(const bf16x8*)(out_WT + (size_t)c * 512 + ks * 32 + g * 8);
    float biav = out_b[c];
    for (int rt = 0; rt < 2; ++rt) {
        f32x4 acc = {};
#pragma unroll
        for (int ks = 0; ks < 16; ++ks) {
            bf16x8 aF = *(const bf16x8*)(Al + (rt * 16 + lr) * 520 + ks * 32 + g * 8);
            acc = MFMA16(aF, wf[ks], acc);
        }
#pragma unroll
        for (int i2 = 0; i2 < 4; ++i2)
            out[(size_t)(rb + rt * 16 + g * 4 + i2) * 256 + c] = acc[i2] + biav;
    }
}

// ---------------------------------------------------------------------------
extern "C" void kernel_launch(void* const* d_in, const int* in_sizes, int n_in,
                              void* d_out, int out_size, void* d_ws, size_t ws_size,
                              hipStream_t stream) {
    const int* tokens = (const int*)d_in[0];
    const int* etok = (const int*)d_in[1];
    const float* node_emb = (const float*)d_in[2];
    const float* edge_emb = (const float*)d_in[3];
    const float* scale_W = (const float*)d_in[4];
    const float* scale_b = (const float*)d_in[5];
    const float* attn_W = (const float*)d_in[6];
    const float* attn_b = (const float*)d_in[7];
    const float* ictx = (const float*)d_in[8];
    const float* inter_W = (const float*)d_in[9];
    const float* inter_b = (const float*)d_in[10];
    const float* ictx2 = (const float*)d_in[11];
    const float* out_W = (const float*)d_in[12];
    const float* out_b = (const float*)d_in[13];
    float* out = (float*)d_out;
    char* ws = (char*)d_ws;

    // ws layout (bytes)
    size_t off = 0;
    bf16* scale_WT = (bf16*)(ws + off); off += 256 * 256 * 2;            // 131072
    bf16* WtopT = (bf16*)(ws + off);    off += 512 * 256 * 2;            // 262144
    bf16* WbotT = (bf16*)(ws + off);    off += 512 * 256 * 2;            // 262144
    bf16* inter_WT = (bf16*)(ws + off); off += 512 * 512 * 2;            // 524288
    bf16* out_WT = (bf16*)(ws + off);   off += 512 * 256 * 2;            // 262144
    float* ce = (float*)(ws + off);     off += 16 * 128 * 4;             // 8192
    float* se = (float*)(ws + off);     off += 16 * 128 * 4;             // 8192
    float* S = (float*)(ws + off);      off += 3 * 512 * 4;              // 6144
    float* scores = (float*)(ws + off); off += 256;
    bf16* scaled_emb = (bf16*)(ws + off); off += (size_t)VN * 256 * 2;   // 25.6 MB
    float* hid = (float*)(ws + off);    off += (size_t)BB * 3 * 512 * 4; // 12.6 MB
    bf16* scanned = (bf16*)(ws + off);
    const size_t chunk_bytes = (size_t)8192 * 8 * 256 * 2;               // 33.55 MB
    size_t need3 = off + chunk_bytes;        // nm=1 (3 passes)
    size_t need1 = off + 3 * chunk_bytes;    // nm=3 (single pass)
    if (ws_size < need3) return;  // insufficient scratch -> fail loudly (zeros)
    const int nm = (ws_size >= need1) ? 3 : 1;

    const int lds_k1 = 64 * 264 * 2;   // 33792
    const int lds_B = 78592;           // Als + h0l + lg2
    const int lds_k4 = 32 * 520 * 2;   // 33280
    (void)hipFuncSetAttribute((const void*)attn_kernel,
                              hipFuncAttributeMaxDynamicSharedMemorySize, lds_B);

    prep_kernel<<<1024, 256, 0, stream>>>(scale_W, attn_W, inter_W, out_W, edge_emb,
                                          scale_WT, WtopT, WbotT, inter_WT, out_WT, ce, se, S);
    emb_gemm_kernel<<<(VN + 63) / 64, 512, lds_k1, stream>>>(node_emb, scale_WT, scale_b,
                                                             scaled_emb);
    for (int m0 = 0; m0 < 3; m0 += nm) {
        scan_kernel<<<nm * 2048, 256, 0, stream>>>(tokens, etok, scaled_emb, ce, se,
                                                   scanned, m0);
        attn_kernel<<<nm * 512, 512, lds_B, stream>>>(scanned, WtopT, WbotT, attn_b, ictx,
                                                      hid, m0);
    }
    inter_kernel<<<dim3(BB / 32, MM), 1024, lds_k4, stream>>>(hid, inter_WT, inter_b, S);
    scores_kernel<<<1, 512, 0, stream>>>(S, ictx2, scores);
    out_kernel<<<BB / 32, 1024, lds_k4, stream>>>(hid, scores, out_WT, out_b, out);
}

// Round 24
// 198.504 us; speedup vs baseline: 1.3235x; 1.0997x over previous
//
#include <hip/hip_runtime.h>
#include <hip/hip_bf16.h>

typedef __bf16 bf16;
typedef bf16 bf16x8 __attribute__((ext_vector_type(8)));
typedef float f32x4 __attribute__((ext_vector_type(4)));

#define MFMA16(a, b, c) __builtin_amdgcn_mfma_f32_16x16x32_bf16((a), (b), (c), 0, 0, 0)

// Problem constants
#define MM 3
#define AA 4
#define BB 2048
#define LL 7
#define HH 256
#define VN 50000

__device__ __forceinline__ float ftanh(float x) {
    float e = __expf(2.f * x);
    float r = __builtin_amdgcn_rcpf(e + 1.f);
    return 1.f - 2.f * r;
}
__device__ __forceinline__ float bf2f(unsigned u) {
    union { unsigned u; float f; } x; x.u = u << 16; return x.f;
}
__device__ __forceinline__ unsigned f2bf(float f) {
    bf16 b = (bf16)f;
    return (unsigned)__builtin_bit_cast(unsigned short, b);
}

// ---------------------------------------------------------------------------
// prep: transposed bf16 weights, cos/sin edge tables, zero S accumulator
// ---------------------------------------------------------------------------
__global__ void prep_kernel(const float* __restrict__ scale_W, const float* __restrict__ attn_W,
                            const float* __restrict__ inter_W, const float* __restrict__ out_W,
                            const float* __restrict__ edge_emb,
                            bf16* __restrict__ scale_WT, bf16* __restrict__ WtopT,
                            bf16* __restrict__ WbotT, bf16* __restrict__ inter_WT,
                            bf16* __restrict__ out_WT,
                            float* __restrict__ ce, float* __restrict__ se,
                            float* __restrict__ S) {
    int idx = blockIdx.x * blockDim.x + threadIdx.x;
    int stride = gridDim.x * blockDim.x;
    for (int i = idx; i < 256 * 256; i += stride) {
        int k = i >> 8, c = i & 255;
        scale_WT[c * 256 + k] = (bf16)scale_W[i];
    }
    for (int i = idx; i < 512 * 256; i += stride) {
        int c = i >> 8, k = i & 255;
        WtopT[c * 256 + k] = (bf16)attn_W[k * 512 + c];
        WbotT[c * 256 + k] = (bf16)attn_W[(256 + k) * 512 + c];
    }
    for (int i = idx; i < 512 * 512; i += stride) {
        int k = i >> 9, c = i & 511;
        inter_WT[c * 512 + k] = (bf16)inter_W[i];
    }
    for (int i = idx; i < 512 * 256; i += stride) {
        int k = i >> 8, c = i & 255;
        out_WT[c * 512 + k] = (bf16)out_W[i];
    }
    for (int i = idx; i < 16 * 128; i += stride) {
        float e = edge_emb[i];
        ce[i] = cosf(e);
        se[i] = sinf(e);
    }
    for (int i = idx; i < 3 * 512; i += stride) S[i] = 0.f;
}

// ---------------------------------------------------------------------------
// K1: scaled_emb[v] = node_emb[v] @ scale_W + scale_b  — 64-row W-in-regs
// ---------------------------------------------------------------------------
__global__ __launch_bounds__(512, 4) void emb_gemm_kernel(
    const float* __restrict__ node_emb, const bf16* __restrict__ scale_WT,
    const float* __restrict__ scale_b, bf16* __restrict__ scaled_emb) {
    extern __shared__ char smem[];
    bf16* Al = (bf16*)smem;  // [64][264] = 33792 B
    const int tid = threadIdx.x;
    const int vb = blockIdx.x * 64;
    const int w = tid >> 6, l = tid & 63, lr = l & 15, g = l >> 4;

    bf16x8 wf[8][2];
#pragma unroll
    for (int ks = 0; ks < 8; ++ks)
#pragma unroll
        for (int ct = 0; ct < 2; ++ct)
            wf[ks][ct] = *(const bf16x8*)(scale_WT + (size_t)(w * 32 + ct * 16 + lr) * 256 +
                                          ks * 32 + g * 8);
    float bia[2];
#pragma unroll
    for (int ct = 0; ct < 2; ++ct) bia[ct] = scale_b[w * 32 + ct * 16 + lr];

    for (int it = 0; it < 8; ++it) {
        int i = tid + it * 512;
        int r = i >> 6, kq = i & 63;
        int v = vb + r;
        float4 x = (v < VN) ? *(const float4*)(node_emb + (size_t)v * 256 + kq * 4)
                            : make_float4(0.f, 0.f, 0.f, 0.f);
        bf16* d = Al + r * 264 + kq * 4;
        d[0] = (bf16)x.x; d[1] = (bf16)x.y; d[2] = (bf16)x.z; d[3] = (bf16)x.w;
    }
    __syncthreads();

    for (int rt = 0; rt < 4; ++rt) {
        f32x4 acc[2] = {};
#pragma unroll
        for (int ks = 0; ks < 8; ++ks) {
            bf16x8 aF = *(const bf16x8*)(Al + (rt * 16 + lr) * 264 + ks * 32 + g * 8);
#pragma unroll
            for (int ct = 0; ct < 2; ++ct) acc[ct] = MFMA16(aF, wf[ks][ct], acc[ct]);
        }
#pragma unroll
        for (int ct = 0; ct < 2; ++ct) {
            int col = w * 32 + ct * 16 + lr;
#pragma unroll
            for (int i2 = 0; i2 < 4; ++i2) {
                int v = vb + rt * 16 + g * 4 + i2;
                if (v < VN) scaled_emb[(size_t)v * 256 + col] = (bf16)(acc[ct][i2] + bia[ct]);
            }
        }
    }
}

// ---------------------------------------------------------------------------
// B: FULLY FUSED gather + rotational scan + attn GEMM + logits + softmax +
//    weighted-sum/relu/a-reduce -> hid. No scanned buffer, no scan kernel.
// Block = 16 n = (4a x 4b), m = bg>>9. Wave w scans q in {2w, 2w+1}, lane
// owns c-pair 2l (same coalescing as old scan_kernel), writing swizzled u32s
// into Als (key = p) and padded h0l (p=0). GEMM/softmax/epilogue = r21.
// ---------------------------------------------------------------------------
__global__ __launch_bounds__(512, 4) void attn_kernel(
    const int* __restrict__ tokens, const int* __restrict__ etok,
    const bf16* __restrict__ scaled_emb, const bf16* __restrict__ WtopT,
    const bf16* __restrict__ WbotT, const float* __restrict__ attn_b,
    const float* __restrict__ ctx, const float* __restrict__ ce,
    const float* __restrict__ se, float* __restrict__ hid) {
    extern __shared__ char smem[];
    bf16* Als = (bf16*)smem;               // 128*256*2 = 65536
    bf16* h0l = (bf16*)(smem + 65536);     // 16*264*2  =  8448
    float* lg2 = (float*)(smem + 73984);   // 128*9*4   =  4608 -> 78592
    const int tid = threadIdx.x;
    const int w = tid >> 6, l = tid & 63, lr = l & 15, g = l >> 4;
    const int bg = blockIdx.x;
    const int m = bg >> 9;                 // 512 b-groups per m
    const int b0 = (bg & 511) * 4;

    // phase 0: gather + scan straight into Als (swizzled) and h0l (padded)
    {
        const int c0 = l * 2;
        const int Lch = c0 >> 3, of = c0 & 7;
#pragma unroll 1
        for (int qq = 0; qq < 2; ++qq) {
            int q = w * 2 + qq;
            int a = q >> 2, bi = q & 3;
            int base = (m * AA + a) * BB + b0 + bi;
            const int* tk = tokens + (base << 3);
            const int* eb = etok + base * LL;
            bf16* arow = Als + (q * 8) * 256;
            unsigned x0r = *(const unsigned*)(scaled_emb + (size_t)tk[0] * 256 + c0);
            unsigned x0i = *(const unsigned*)(scaled_emb + (size_t)tk[0] * 256 + c0 + 128);
            *(unsigned*)(arow + Lch * 8 + of) = x0r;          // p=0: identity key
            *(unsigned*)(arow + (Lch + 16) * 8 + of) = x0i;
            *(unsigned*)(h0l + q * 264 + c0) = x0r;
            *(unsigned*)(h0l + q * 264 + c0 + 128) = x0i;
            float Sr0 = bf2f(x0r & 0xffffu), Sr1 = bf2f(x0r >> 16);
            float Si0 = bf2f(x0i & 0xffffu), Si1 = bf2f(x0i >> 16);
            float P0r = 1.f, P0i = 0.f, P1r = 1.f, P1i = 0.f;
#pragma unroll
            for (int k = 1; k <= LL; ++k) {
                int e = eb[k - 1];
                int v = tk[k];
                float2 crv = *(const float2*)(ce + e * 128 + c0);
                float2 civ = *(const float2*)(se + e * 128 + c0);
                float t0r = P0r * crv.x - P0i * civ.x, t0i = P0r * civ.x + P0i * crv.x;
                float t1r = P1r * crv.y - P1i * civ.y, t1i = P1r * civ.y + P1i * crv.y;
                P0r = t0r; P0i = t0i; P1r = t1r; P1i = t1i;
                unsigned xr = *(const unsigned*)(scaled_emb + (size_t)v * 256 + c0);
                unsigned xi = *(const unsigned*)(scaled_emb + (size_t)v * 256 + c0 + 128);
                float xr0 = bf2f(xr & 0xffffu), xr1 = bf2f(xr >> 16);
                float xi0 = bf2f(xi & 0xffffu), xi1 = bf2f(xi >> 16);
                Sr0 += P0r * xr0 - P0i * xi0; Si0 += P0r * xi0 + P0i * xr0;
                Sr1 += P1r * xr1 - P1i * xi1; Si1 += P1r * xi1 + P1i * xr1;
                float inv = 1.f / (float)(k + 1);
                bf16* rowk = Als + (q * 8 + k) * 256;
                *(unsigned*)(rowk + ((Lch ^ k) << 3) + of) =
                    f2bf(Sr0 * inv) | (f2bf(Sr1 * inv) << 16);
                *(unsigned*)(rowk + (((Lch + 16) ^ k) << 3) + of) =
                    f2bf(Si0 * inv) | (f2bf(Si1 * inv) << 16);
            }
        }
    }
    __syncthreads();

    const int bsel = g >> 1;
    float pv[8][4] = {};
#pragma unroll 1
    for (int cc = 0; cc < 4; ++cc) {
        const int cb = cc * 128 + w * 16;
        // y0 = h0 . Wtop for 16 n's — A from padded h0l (conflict-free)
        f32x4 a0 = {};
        {
            bf16x8 wt[8];
#pragma unroll
            for (int ks = 0; ks < 8; ++ks)
                wt[ks] = *(const bf16x8*)(WtopT + (size_t)(cb + lr) * 256 + ks * 32 + g * 8);
#pragma unroll
            for (int ks = 0; ks < 8; ++ks) {
                bf16x8 aF = *(const bf16x8*)(h0l + lr * 264 + ks * 32 + g * 8);
                a0 = MFMA16(aF, wt[ks], a0);
            }
        }
        // broadcast y0[q][lane's col] from producer lanes (static reg indices)
        float y0sel[8];
#pragma unroll
        for (int rt = 0; rt < 8; ++rt) {
            float t0 = __shfl(a0[(2 * rt) & 3], (((2 * rt) >> 2) << 4) + lr, 64);
            float t1 = __shfl(a0[(2 * rt + 1) & 3], (((2 * rt + 1) >> 2) << 4) + lr, 64);
            y0sel[rt] = bsel ? t1 : t0;
        }
        bf16x8 wb[8];
#pragma unroll
        for (int ks = 0; ks < 8; ++ks)
            wb[ks] = *(const bf16x8*)(WbotT + (size_t)(cb + lr) * 256 + ks * 32 + g * 8);
        float bia = attn_b[cb + lr];
        float cxv = ctx[cb + lr];
#pragma unroll
        for (int rt = 0; rt < 8; ++rt) {
            float y0v = y0sel[rt];
            f32x4 accE, accO;
            accE[0] = y0v; accE[1] = y0v; accE[2] = y0v; accE[3] = y0v;
            accO[0] = 0.f; accO[1] = 0.f; accO[2] = 0.f; accO[3] = 0.f;
            __builtin_amdgcn_s_setprio(1);
#pragma unroll
            for (int ks = 0; ks < 4; ++ks) {
                bf16x8 aE = *(const bf16x8*)(Als + (rt * 16 + lr) * 256 +
                                             ((((2 * ks) * 4 + g) ^ (lr & 7)) << 3));
                bf16x8 aO = *(const bf16x8*)(Als + (rt * 16 + lr) * 256 +
                                             ((((2 * ks + 1) * 4 + g) ^ (lr & 7)) << 3));
                accE = MFMA16(aE, wb[2 * ks], accE);
                accO = MFMA16(aO, wb[2 * ks + 1], accO);
            }
            __builtin_amdgcn_s_setprio(0);
#pragma unroll
            for (int i2 = 0; i2 < 4; ++i2)
                pv[rt][i2] += cxv * ftanh(accE[i2] + accO[i2] + bia);
        }
        __builtin_amdgcn_sched_barrier(0);
    }
    // reduce logit partials over 16 column-lanes
#pragma unroll
    for (int msk = 1; msk < 16; msk <<= 1)
#pragma unroll
        for (int rt = 0; rt < 8; ++rt)
#pragma unroll
            for (int i2 = 0; i2 < 4; ++i2) pv[rt][i2] += __shfl_xor(pv[rt][i2], msk, 64);
    if (lr == 0) {
#pragma unroll
        for (int rt = 0; rt < 8; ++rt)
#pragma unroll
            for (int i2 = 0; i2 < 4; ++i2) {
                int row = rt * 16 + g * 4 + i2;
                if (row & 7) lg2[row * 9 + w] = pv[rt][i2];
            }
    }
    __syncthreads();

    // softmax per q (7 positions) -> weights in lg2 column 8
    if (tid < 16) {
        int q = tid;
        float lv[LL], mx = -1e30f;
#pragma unroll
        for (int j = 1; j <= LL; ++j) {
            float sv = 0.f;
#pragma unroll
            for (int w8 = 0; w8 < 8; ++w8) sv += lg2[(q * 8 + j) * 9 + w8];
            lv[j - 1] = sv;
            mx = fmaxf(mx, sv);
        }
        float ssum = 0.f, ev[LL];
#pragma unroll
        for (int j = 0; j < LL; ++j) { ev[j] = __expf(lv[j] - mx); ssum += ev[j]; }
        float inv = 1.f / ssum;
#pragma unroll
        for (int j = 0; j < LL; ++j) lg2[(q * 8 + j + 1) * 9 + 8] = ev[j] * inv;
    }
    __syncthreads();

    // fused epilogue: hid[b0+bi][m][c] = sum_a relu([h0 | sum_j w_j h_j])
    for (int it2 = 0; it2 < 2; ++it2) {
        int item = tid + it2 * 512;    // 0..1023 = 4 bi x 256 c-pairs
        int bi = item >> 8, cp = item & 255;
        int c0 = cp * 2;
        float acc0 = 0.f, acc1 = 0.f;
        if (c0 < 256) {
#pragma unroll
            for (int a = 0; a < AA; ++a) {
                int q = a * 4 + bi;
                unsigned u = *(const unsigned*)(Als + q * 2048 + c0);  // p=0 row, key 0
                acc0 += fmaxf(0.f, bf2f(u & 0xffffu));
                acc1 += fmaxf(0.f, bf2f(u >> 16));
            }
        } else {
            int cb2 = c0 - 256;
            int ch = cb2 >> 3, of = cb2 & 7;
#pragma unroll
            for (int a = 0; a < AA; ++a) {
                int q = a * 4 + bi;
                float s0 = 0.f, s1 = 0.f;
#pragma unroll
                for (int j = 1; j <= LL; ++j) {
                    unsigned u = *(const unsigned*)(Als + (q * 8 + j) * 256 +
                                                    ((ch ^ j) << 3) + of);
                    float wj = lg2[(q * 8 + j) * 9 + 8];
                    s0 += wj * bf2f(u & 0xffffu);
                    s1 += wj * bf2f(u >> 16);
                }
                acc0 += fmaxf(0.f, s0);
                acc1 += fmaxf(0.f, s1);
            }
        }
        float2 o; o.x = acc0; o.y = acc1;
        *(float2*)(hid + ((size_t)(b0 + bi) * 3 + m) * 512 + c0) = o;
    }
}

// ---------------------------------------------------------------------------
// K4a: S[m][c] += sum_b tanh(hid[b][m] . inter_W[:,c] + inter_b[c])
// ---------------------------------------------------------------------------
__global__ __launch_bounds__(1024, 4) void inter_kernel(
    const float* __restrict__ hid, const bf16* __restrict__ inter_WT,
    const float* __restrict__ inter_b, float* __restrict__ S) {
    extern __shared__ char smem[];
    bf16* Al = (bf16*)smem;  // [32][520] = 33280 B
    const int tid = threadIdx.x;
    const int m = blockIdx.y, rb = blockIdx.x * 32;
    const int w = tid >> 6, l = tid & 63, lr = l & 15, g = l >> 4;
    for (int it = 0; it < 4; ++it) {
        int i = tid + it * 1024;
        int r = i >> 7, kq = i & 127;
        float4 x = *(const float4*)(hid + ((size_t)(rb + r) * 3 + m) * 512 + kq * 4);
        bf16* d = Al + r * 520 + kq * 4;
        d[0] = (bf16)x.x; d[1] = (bf16)x.y; d[2] = (bf16)x.z; d[3] = (bf16)x.w;
    }
    __syncthreads();
#pragma unroll 1
    for (int cc = 0; cc < 2; ++cc) {
        int c = cc * 256 + w * 16 + lr;
        bf16x8 wf[16];
#pragma unroll
        for (int ks = 0; ks < 16; ++ks)
            wf[ks] = *(const bf16x8*)(inter_WT + (size_t)c * 512 + ks * 32 + g * 8);
        float biav = inter_b[c];
        float csum = 0.f;
        for (int rt = 0; rt < 2; ++rt) {
            f32x4 acc = {};
#pragma unroll
            for (int ks = 0; ks < 16; ++ks) {
                bf16x8 aF = *(const bf16x8*)(Al + (rt * 16 + lr) * 520 + ks * 32 + g * 8);
                acc = MFMA16(aF, wf[ks], acc);
            }
#pragma unroll
            for (int i2 = 0; i2 < 4; ++i2) csum += ftanh(acc[i2] + biav);
        }
        csum += __shfl_xor(csum, 16, 64);
        csum += __shfl_xor(csum, 32, 64);
        if (g == 0) atomicAdd(&S[m * 512 + c], csum);
        __builtin_amdgcn_sched_barrier(0);
    }
}

// ---------------------------------------------------------------------------
// K4b: scores[m] = (sum_c S[m][c] * inter_context[c]) / 2048
// ---------------------------------------------------------------------------
__global__ void scores_kernel(const float* __restrict__ S, const float* __restrict__ ictx2,
                              float* __restrict__ scores) {
    __shared__ float red[512];
    int t = threadIdx.x;
    for (int m = 0; m < 3; ++m) {
        red[t] = S[m * 512 + t] * ictx2[t];
        __syncthreads();
        for (int st = 256; st > 0; st >>= 1) {
            if (t < st) red[t] += red[t + st];
            __syncthreads();
        }
        if (t == 0) scores[m] = red[0] * (1.f / 2048.f);
        __syncthreads();
    }
}

// ---------------------------------------------------------------------------
// K4c: out[b] = (sum_m hid[b][m] * scores[m]) @ out_W + out_b
// ---------------------------------------------------------------------------
__global__ __launch_bounds__(1024, 4) void out_kernel(
    const float* __restrict__ hid, const float* __restrict__ scores,
    const bf16* __restrict__ out_WT, const float* __restrict__ out_b,
    float* __restrict__ out) {
    extern __shared__ char smem[];
    bf16* Al = (bf16*)smem;  // [32][520] = 33280 B
    const int tid = threadIdx.x;
    const int rb = blockIdx.x * 32;
    const int w = tid >> 6, l = tid & 63, lr = l & 15, g = l >> 4;
    float s0 = scores[0], s1 = scores[1], s2 = scores[2];
    for (int it = 0; it < 4; ++it) {
        int i = tid + it * 1024;
        int r = i >> 7, kq = i & 127;
        const float* hp = hid + (size_t)(rb + r) * 1536 + kq * 4;
        float4 x0 = *(const float4*)(hp);
        float4 x1 = *(const float4*)(hp + 512);
        float4 x2 = *(const float4*)(hp + 1024);
        bf16* d = Al + r * 520 + kq * 4;
        d[0] = (bf16)(x0.x * s0 + x1.x * s1 + x2.x * s2);
        d[1] = (bf16)(x0.y * s0 + x1.y * s1 + x2.y * s2);
        d[2] = (bf16)(x0.z * s0 + x1.z * s1 + x2.z * s2);
        d[3] = (bf16)(x0.w * s0 + x1.w * s1 + x2.w * s2);
    }
    __syncthreads();
    int c = w * 16 + lr;
    bf16x8 wf[16];
#pragma unroll
    for (int ks = 0; ks < 16; ++ks)
        wf[ks] = *(const bf16x8*)(out_WT + (size_t)c * 512 + ks * 32 + g * 8);
    float biav = out_b[c];
    for (int rt = 0; rt < 2; ++rt) {
        f32x4 acc = {};
#pragma unroll
        for (int ks = 0; ks < 16; ++ks) {
            bf16x8 aF = *(const bf16x8*)(Al + (rt * 16 + lr) * 520 + ks * 32 + g * 8);
            acc = MFMA16(aF, wf[ks], acc);
        }
#pragma unroll
        for (int i2 = 0; i2 < 4; ++i2)
            out[(size_t)(rb + rt * 16 + g * 4 + i2) * 256 + c] = acc[i2] + biav;
    }
}

// ---------------------------------------------------------------------------
extern "C" void kernel_launch(void* const* d_in, const int* in_sizes, int n_in,
                              void* d_out, int out_size, void* d_ws, size_t ws_size,
                              hipStream_t stream) {
    const int* tokens = (const int*)d_in[0];
    const int* etok = (const int*)d_in[1];
    const float* node_emb = (const float*)d_in[2];
    const float* edge_emb = (const float*)d_in[3];
    const float* scale_W = (const float*)d_in[4];
    const float* scale_b = (const float*)d_in[5];
    const float* attn_W = (const float*)d_in[6];
    const float* attn_b = (const float*)d_in[7];
    const float* ictx = (const float*)d_in[8];
    const float* inter_W = (const float*)d_in[9];
    const float* inter_b = (const float*)d_in[10];
    const float* ictx2 = (const float*)d_in[11];
    const float* out_W = (const float*)d_in[12];
    const float* out_b = (const float*)d_in[13];
    float* out = (float*)d_out;
    char* ws = (char*)d_ws;

    // ws layout (bytes) — scanned buffer eliminated (~39.6 MB total)
    size_t off = 0;
    bf16* scale_WT = (bf16*)(ws + off); off += 256 * 256 * 2;            // 131072
    bf16* WtopT = (bf16*)(ws + off);    off += 512 * 256 * 2;            // 262144
    bf16* WbotT = (bf16*)(ws + off);    off += 512 * 256 * 2;            // 262144
    bf16* inter_WT = (bf16*)(ws + off); off += 512 * 512 * 2;            // 524288
    bf16* out_WT = (bf16*)(ws + off);   off += 512 * 256 * 2;            // 262144
    float* ce = (float*)(ws + off);     off += 16 * 128 * 4;             // 8192
    float* se = (float*)(ws + off);     off += 16 * 128 * 4;             // 8192
    float* S = (float*)(ws + off);      off += 3 * 512 * 4;              // 6144
    float* scores = (float*)(ws + off); off += 256;
    bf16* scaled_emb = (bf16*)(ws + off); off += (size_t)VN * 256 * 2;   // 25.6 MB
    float* hid = (float*)(ws + off);    off += (size_t)BB * 3 * 512 * 4; // 12.6 MB
    if (ws_size < off) return;  // insufficient scratch -> fail loudly (zeros)

    const int lds_k1 = 64 * 264 * 2;   // 33792
    const int lds_B = 78592;           // Als + h0l + lg2
    const int lds_k4 = 32 * 520 * 2;   // 33280
    (void)hipFuncSetAttribute((const void*)attn_kernel,
                              hipFuncAttributeMaxDynamicSharedMemorySize, lds_B);

    prep_kernel<<<1024, 256, 0, stream>>>(scale_W, attn_W, inter_W, out_W, edge_emb,
                                          scale_WT, WtopT, WbotT, inter_WT, out_WT, ce, se, S);
    emb_gemm_kernel<<<(VN + 63) / 64, 512, lds_k1, stream>>>(node_emb, scale_WT, scale_b,
                                                             scaled_emb);
    attn_kernel<<<3 * 512, 512, lds_B, stream>>>(tokens, etok, scaled_emb, WtopT, WbotT,
                                                 attn_b, ictx, ce, se, hid);
    inter_kernel<<<dim3(BB / 32, MM), 1024, lds_k4, stream>>>(hid, inter_WT, inter_b, S);
    scores_kernel<<<1, 512, 0, stream>>>(S, ictx2, scores);
    out_kernel<<<BB / 32, 1024, lds_k4, stream>>>(hid, scores, out_WT, out_b, out);
}

// Round 25
// 198.161 us; speedup vs baseline: 1.3258x; 1.0017x over previous
//
#include <hip/hip_runtime.h>
#include <hip/hip_bf16.h>

typedef __bf16 bf16;
typedef bf16 bf16x8 __attribute__((ext_vector_type(8)));
typedef float f32x4 __attribute__((ext_vector_type(4)));

#define MFMA16(a, b, c) __builtin_amdgcn_mfma_f32_16x16x32_bf16((a), (b), (c), 0, 0, 0)

// Problem constants
#define MM 3
#define AA 4
#define BB 2048
#define LL 7
#define HH 256
#define VN 50000

__device__ __forceinline__ float ftanh(float x) {
    float e = __expf(2.f * x);
    float r = __builtin_amdgcn_rcpf(e + 1.f);
    return 1.f - 2.f * r;
}
__device__ __forceinline__ float bf2f(unsigned u) {
    union { unsigned u; float f; } x; x.u = u << 16; return x.f;
}
__device__ __forceinline__ unsigned f2bf(float f) {
    bf16 b = (bf16)f;
    return (unsigned)__builtin_bit_cast(unsigned short, b);
}

// ---------------------------------------------------------------------------
// prep: transposed bf16 weights, cos/sin edge tables, zero S accumulator
// ---------------------------------------------------------------------------
__global__ void prep_kernel(const float* __restrict__ scale_W, const float* __restrict__ attn_W,
                            const float* __restrict__ inter_W, const float* __restrict__ out_W,
                            const float* __restrict__ edge_emb,
                            bf16* __restrict__ scale_WT, bf16* __restrict__ WtopT,
                            bf16* __restrict__ WbotT, bf16* __restrict__ inter_WT,
                            bf16* __restrict__ out_WT,
                            float* __restrict__ ce, float* __restrict__ se,
                            float* __restrict__ S) {
    int idx = blockIdx.x * blockDim.x + threadIdx.x;
    int stride = gridDim.x * blockDim.x;
    for (int i = idx; i < 256 * 256; i += stride) {
        int k = i >> 8, c = i & 255;
        scale_WT[c * 256 + k] = (bf16)scale_W[i];
    }
    for (int i = idx; i < 512 * 256; i += stride) {
        int c = i >> 8, k = i & 255;
        WtopT[c * 256 + k] = (bf16)attn_W[k * 512 + c];
        WbotT[c * 256 + k] = (bf16)attn_W[(256 + k) * 512 + c];
    }
    for (int i = idx; i < 512 * 512; i += stride) {
        int k = i >> 9, c = i & 511;
        inter_WT[c * 512 + k] = (bf16)inter_W[i];
    }
    for (int i = idx; i < 512 * 256; i += stride) {
        int k = i >> 8, c = i & 255;
        out_WT[c * 512 + k] = (bf16)out_W[i];
    }
    for (int i = idx; i < 16 * 128; i += stride) {
        float e = edge_emb[i];
        ce[i] = cosf(e);
        se[i] = sinf(e);
    }
    for (int i = idx; i < 3 * 512; i += stride) S[i] = 0.f;
}

// ---------------------------------------------------------------------------
// K1: scaled_emb[v] = node_emb[v] @ scale_W + scale_b  — 64-row W-in-regs
// ---------------------------------------------------------------------------
__global__ __launch_bounds__(512, 4) void emb_gemm_kernel(
    const float* __restrict__ node_emb, const bf16* __restrict__ scale_WT,
    const float* __restrict__ scale_b, bf16* __restrict__ scaled_emb) {
    extern __shared__ char smem[];
    bf16* Al = (bf16*)smem;  // [64][264] = 33792 B
    const int tid = threadIdx.x;
    const int vb = blockIdx.x * 64;
    const int w = tid >> 6, l = tid & 63, lr = l & 15, g = l >> 4;

    bf16x8 wf[8][2];
#pragma unroll
    for (int ks = 0; ks < 8; ++ks)
#pragma unroll
        for (int ct = 0; ct < 2; ++ct)
            wf[ks][ct] = *(const bf16x8*)(scale_WT + (size_t)(w * 32 + ct * 16 + lr) * 256 +
                                          ks * 32 + g * 8);
    float bia[2];
#pragma unroll
    for (int ct = 0; ct < 2; ++ct) bia[ct] = scale_b[w * 32 + ct * 16 + lr];

    for (int it = 0; it < 8; ++it) {
        int i = tid + it * 512;
        int r = i >> 6, kq = i & 63;
        int v = vb + r;
        float4 x = (v < VN) ? *(const float4*)(node_emb + (size_t)v * 256 + kq * 4)
                            : make_float4(0.f, 0.f, 0.f, 0.f);
        bf16* d = Al + r * 264 + kq * 4;
        d[0] = (bf16)x.x; d[1] = (bf16)x.y; d[2] = (bf16)x.z; d[3] = (bf16)x.w;
    }
    __syncthreads();

    for (int rt = 0; rt < 4; ++rt) {
        f32x4 acc[2] = {};
#pragma unroll
        for (int ks = 0; ks < 8; ++ks) {
            bf16x8 aF = *(const bf16x8*)(Al + (rt * 16 + lr) * 264 + ks * 32 + g * 8);
#pragma unroll
            for (int ct = 0; ct < 2; ++ct) acc[ct] = MFMA16(aF, wf[ks][ct], acc[ct]);
        }
#pragma unroll
        for (int ct = 0; ct < 2; ++ct) {
            int col = w * 32 + ct * 16 + lr;
#pragma unroll
            for (int i2 = 0; i2 < 4; ++i2) {
                int v = vb + rt * 16 + g * 4 + i2;
                if (v < VN) scaled_emb[(size_t)v * 256 + col] = (bf16)(acc[ct][i2] + bia[ct]);
            }
        }
    }
}

// ---------------------------------------------------------------------------
// B: FULLY FUSED gather + rotational scan + attn GEMM + logits + softmax +
//    weighted-sum/relu/a-reduce -> hid. No scanned buffer, no scan kernel.
// Block = 16 n = (4a x 4b), m = bg>>9. Wave w scans q in {2w, 2w+1}, lane
// owns c-pair 2l; the two chains are INTERLEAVED (full unroll) for 2x MLP
// in the 7-step dependent-load scan. GEMM/softmax/epilogue = r24.
// ---------------------------------------------------------------------------
__global__ __launch_bounds__(512, 4) void attn_kernel(
    const int* __restrict__ tokens, const int* __restrict__ etok,
    const bf16* __restrict__ scaled_emb, const bf16* __restrict__ WtopT,
    const bf16* __restrict__ WbotT, const float* __restrict__ attn_b,
    const float* __restrict__ ctx, const float* __restrict__ ce,
    const float* __restrict__ se, float* __restrict__ hid) {
    extern __shared__ char smem[];
    bf16* Als = (bf16*)smem;               // 128*256*2 = 65536
    bf16* h0l = (bf16*)(smem + 65536);     // 16*264*2  =  8448
    float* lg2 = (float*)(smem + 73984);   // 128*9*4   =  4608 -> 78592
    const int tid = threadIdx.x;
    const int w = tid >> 6, l = tid & 63, lr = l & 15, g = l >> 4;
    const int bg = blockIdx.x;
    const int m = bg >> 9;                 // 512 b-groups per m
    const int b0 = (bg & 511) * 4;

    // phase 0: gather + scan straight into Als (swizzled) and h0l (padded);
    // the two q-chains per wave are interleaved by full unroll (independent).
    {
        const int c0 = l * 2;
        const int Lch = c0 >> 3, of = c0 & 7;
#pragma unroll
        for (int qq = 0; qq < 2; ++qq) {
            int q = w * 2 + qq;
            int a = q >> 2, bi = q & 3;
            int base = (m * AA + a) * BB + b0 + bi;
            const int* tk = tokens + (base << 3);
            const int* eb = etok + base * LL;
            bf16* arow = Als + (q * 8) * 256;
            unsigned x0r = *(const unsigned*)(scaled_emb + (size_t)tk[0] * 256 + c0);
            unsigned x0i = *(const unsigned*)(scaled_emb + (size_t)tk[0] * 256 + c0 + 128);
            *(unsigned*)(arow + Lch * 8 + of) = x0r;          // p=0: identity key
            *(unsigned*)(arow + (Lch + 16) * 8 + of) = x0i;
            *(unsigned*)(h0l + q * 264 + c0) = x0r;
            *(unsigned*)(h0l + q * 264 + c0 + 128) = x0i;
            float Sr0 = bf2f(x0r & 0xffffu), Sr1 = bf2f(x0r >> 16);
            float Si0 = bf2f(x0i & 0xffffu), Si1 = bf2f(x0i >> 16);
            float P0r = 1.f, P0i = 0.f, P1r = 1.f, P1i = 0.f;
#pragma unroll
            for (int k = 1; k <= LL; ++k) {
                int e = eb[k - 1];
                int v = tk[k];
                float2 crv = *(const float2*)(ce + e * 128 + c0);
                float2 civ = *(const float2*)(se + e * 128 + c0);
                float t0r = P0r * crv.x - P0i * civ.x, t0i = P0r * civ.x + P0i * crv.x;
                float t1r = P1r * crv.y - P1i * civ.y, t1i = P1r * civ.y + P1i * crv.y;
                P0r = t0r; P0i = t0i; P1r = t1r; P1i = t1i;
                unsigned xr = *(const unsigned*)(scaled_emb + (size_t)v * 256 + c0);
                unsigned xi = *(const unsigned*)(scaled_emb + (size_t)v * 256 + c0 + 128);
                float xr0 = bf2f(xr & 0xffffu), xr1 = bf2f(xr >> 16);
                float xi0 = bf2f(xi & 0xffffu), xi1 = bf2f(xi >> 16);
                Sr0 += P0r * xr0 - P0i * xi0; Si0 += P0r * xi0 + P0i * xr0;
                Sr1 += P1r * xr1 - P1i * xi1; Si1 += P1r * xi1 + P1i * xr1;
                float inv = 1.f / (float)(k + 1);
                bf16* rowk = Als + (q * 8 + k) * 256;
                *(unsigned*)(rowk + ((Lch ^ k) << 3) + of) =
                    f2bf(Sr0 * inv) | (f2bf(Sr1 * inv) << 16);
                *(unsigned*)(rowk + (((Lch + 16) ^ k) << 3) + of) =
                    f2bf(Si0 * inv) | (f2bf(Si1 * inv) << 16);
            }
        }
    }
    __syncthreads();

    const int bsel = g >> 1;
    float pv[8][4] = {};
#pragma unroll 1
    for (int cc = 0; cc < 4; ++cc) {
        const int cb = cc * 128 + w * 16;
        // y0 = h0 . Wtop for 16 n's — A from padded h0l (conflict-free)
        f32x4 a0 = {};
        {
            bf16x8 wt[8];
#pragma unroll
            for (int ks = 0; ks < 8; ++ks)
                wt[ks] = *(const bf16x8*)(WtopT + (size_t)(cb + lr) * 256 + ks * 32 + g * 8);
#pragma unroll
            for (int ks = 0; ks < 8; ++ks) {
                bf16x8 aF = *(const bf16x8*)(h0l + lr * 264 + ks * 32 + g * 8);
                a0 = MFMA16(aF, wt[ks], a0);
            }
        }
        // broadcast y0[q][lane's col] from producer lanes (static reg indices)
        float y0sel[8];
#pragma unroll
        for (int rt = 0; rt < 8; ++rt) {
            float t0 = __shfl(a0[(2 * rt) & 3], (((2 * rt) >> 2) << 4) + lr, 64);
            float t1 = __shfl(a0[(2 * rt + 1) & 3], (((2 * rt + 1) >> 2) << 4) + lr, 64);
            y0sel[rt] = bsel ? t1 : t0;
        }
        bf16x8 wb[8];
#pragma unroll
        for (int ks = 0; ks < 8; ++ks)
            wb[ks] = *(const bf16x8*)(WbotT + (size_t)(cb + lr) * 256 + ks * 32 + g * 8);
        float bia = attn_b[cb + lr];
        float cxv = ctx[cb + lr];
#pragma unroll
        for (int rt = 0; rt < 8; ++rt) {
            float y0v = y0sel[rt];
            f32x4 accE, accO;
            accE[0] = y0v; accE[1] = y0v; accE[2] = y0v; accE[3] = y0v;
            accO[0] = 0.f; accO[1] = 0.f; accO[2] = 0.f; accO[3] = 0.f;
            __builtin_amdgcn_s_setprio(1);
#pragma unroll
            for (int ks = 0; ks < 4; ++ks) {
                bf16x8 aE = *(const bf16x8*)(Als + (rt * 16 + lr) * 256 +
                                             ((((2 * ks) * 4 + g) ^ (lr & 7)) << 3));
                bf16x8 aO = *(const bf16x8*)(Als + (rt * 16 + lr) * 256 +
                                             ((((2 * ks + 1) * 4 + g) ^ (lr & 7)) << 3));
                accE = MFMA16(aE, wb[2 * ks], accE);
                accO = MFMA16(aO, wb[2 * ks + 1], accO);
            }
            __builtin_amdgcn_s_setprio(0);
#pragma unroll
            for (int i2 = 0; i2 < 4; ++i2)
                pv[rt][i2] += cxv * ftanh(accE[i2] + accO[i2] + bia);
        }
        __builtin_amdgcn_sched_barrier(0);
    }
    // reduce logit partials over 16 column-lanes
#pragma unroll
    for (int msk = 1; msk < 16; msk <<= 1)
#pragma unroll
        for (int rt = 0; rt < 8; ++rt)
#pragma unroll
            for (int i2 = 0; i2 < 4; ++i2) pv[rt][i2] += __shfl_xor(pv[rt][i2], msk, 64);
    if (lr == 0) {
#pragma unroll
        for (int rt = 0; rt < 8; ++rt)
#pragma unroll
            for (int i2 = 0; i2 < 4; ++i2) {
                int row = rt * 16 + g * 4 + i2;
                if (row & 7) lg2[row * 9 + w] = pv[rt][i2];
            }
    }
    __syncthreads();

    // softmax per q (7 positions) -> weights in lg2 column 8
    if (tid < 16) {
        int q = tid;
        float lv[LL], mx = -1e30f;
#pragma unroll
        for (int j = 1; j <= LL; ++j) {
            float sv = 0.f;
#pragma unroll
            for (int w8 = 0; w8 < 8; ++w8) sv += lg2[(q * 8 + j) * 9 + w8];
            lv[j - 1] = sv;
            mx = fmaxf(mx, sv);
        }
        float ssum = 0.f, ev[LL];
#pragma unroll
        for (int j = 0; j < LL; ++j) { ev[j] = __expf(lv[j] - mx); ssum += ev[j]; }
        float inv = 1.f / ssum;
#pragma unroll
        for (int j = 0; j < LL; ++j) lg2[(q * 8 + j + 1) * 9 + 8] = ev[j] * inv;
    }
    __syncthreads();

    // fused epilogue: hid[b0+bi][m][c] = sum_a relu([h0 | sum_j w_j h_j])
    for (int it2 = 0; it2 < 2; ++it2) {
        int item = tid + it2 * 512;    // 0..1023 = 4 bi x 256 c-pairs
        int bi = item >> 8, cp = item & 255;
        int c0 = cp * 2;
        float acc0 = 0.f, acc1 = 0.f;
        if (c0 < 256) {
#pragma unroll
            for (int a = 0; a < AA; ++a) {
                int q = a * 4 + bi;
                unsigned u = *(const unsigned*)(Als + q * 2048 + c0);  // p=0 row, key 0
                acc0 += fmaxf(0.f, bf2f(u & 0xffffu));
                acc1 += fmaxf(0.f, bf2f(u >> 16));
            }
        } else {
            int cb2 = c0 - 256;
            int ch = cb2 >> 3, of = cb2 & 7;
#pragma unroll
            for (int a = 0; a < AA; ++a) {
                int q = a * 4 + bi;
                float s0 = 0.f, s1 = 0.f;
#pragma unroll
                for (int j = 1; j <= LL; ++j) {
                    unsigned u = *(const unsigned*)(Als + (q * 8 + j) * 256 +
                                                    ((ch ^ j) << 3) + of);
                    float wj = lg2[(q * 8 + j) * 9 + 8];
                    s0 += wj * bf2f(u & 0xffffu);
                    s1 += wj * bf2f(u >> 16);
                }
                acc0 += fmaxf(0.f, s0);
                acc1 += fmaxf(0.f, s1);
            }
        }
        float2 o; o.x = acc0; o.y = acc1;
        *(float2*)(hid + ((size_t)(b0 + bi) * 3 + m) * 512 + c0) = o;
    }
}

// ---------------------------------------------------------------------------
// K4a: S[m][c] += sum_b tanh(hid[b][m] . inter_W[:,c] + inter_b[c])
// ---------------------------------------------------------------------------
__global__ __launch_bounds__(1024, 4) void inter_kernel(
    const float* __restrict__ hid, const bf16* __restrict__ inter_WT,
    const float* __restrict__ inter_b, float* __restrict__ S) {
    extern __shared__ char smem[];
    bf16* Al = (bf16*)smem;  // [32][520] = 33280 B
    const int tid = threadIdx.x;
    const int m = blockIdx.y, rb = blockIdx.x * 32;
    const int w = tid >> 6, l = tid & 63, lr = l & 15, g = l >> 4;
    for (int it = 0; it < 4; ++it) {
        int i = tid + it * 1024;
        int r = i >> 7, kq = i & 127;
        float4 x = *(const float4*)(hid + ((size_t)(rb + r) * 3 + m) * 512 + kq * 4);
        bf16* d = Al + r * 520 + kq * 4;
        d[0] = (bf16)x.x; d[1] = (bf16)x.y; d[2] = (bf16)x.z; d[3] = (bf16)x.w;
    }
    __syncthreads();
#pragma unroll 1
    for (int cc = 0; cc < 2; ++cc) {
        int c = cc * 256 + w * 16 + lr;
        bf16x8 wf[16];
#pragma unroll
        for (int ks = 0; ks < 16; ++ks)
            wf[ks] = *(const bf16x8*)(inter_WT + (size_t)c * 512 + ks * 32 + g * 8);
        float biav = inter_b[c];
        float csum = 0.f;
        for (int rt = 0; rt < 2; ++rt) {
            f32x4 acc = {};
#pragma unroll
            for (int ks = 0; ks < 16; ++ks) {
                bf16x8 aF = *(const bf16x8*)(Al + (rt * 16 + lr) * 520 + ks * 32 + g * 8);
                acc = MFMA16(aF, wf[ks], acc);
            }
#pragma unroll
            for (int i2 = 0; i2 < 4; ++i2) csum += ftanh(acc[i2] + biav);
        }
        csum += __shfl_xor(csum, 16, 64);
        csum += __shfl_xor(csum, 32, 64);
        if (g == 0) atomicAdd(&S[m * 512 + c], csum);
        __builtin_amdgcn_sched_barrier(0);
    }
}

// ---------------------------------------------------------------------------
// K4b: scores[m] = (sum_c S[m][c] * inter_context[c]) / 2048
// ---------------------------------------------------------------------------
__global__ void scores_kernel(const float* __restrict__ S, const float* __restrict__ ictx2,
                              float* __restrict__ scores) {
    __shared__ float red[512];
    int t = threadIdx.x;
    for (int m = 0; m < 3; ++m) {
        red[t] = S[m * 512 + t] * ictx2[t];
        __syncthreads();
        for (int st = 256; st > 0; st >>= 1) {
            if (t < st) red[t] += red[t + st];
            __syncthreads();
        }
        if (t == 0) scores[m] = red[0] * (1.f / 2048.f);
        __syncthreads();
    }
}

// ---------------------------------------------------------------------------
// K4c: out[b] = (sum_m hid[b][m] * scores[m]) @ out_W + out_b
// ---------------------------------------------------------------------------
__global__ __launch_bounds__(1024, 4) void out_kernel(
    const float* __restrict__ hid, const float* __restrict__ scores,
    const bf16* __restrict__ out_WT, const float* __restrict__ out_b,
    float* __restrict__ out) {
    extern __shared__ char smem[];
    bf16* Al = (bf16*)smem;  // [32][520] = 33280 B
    const int tid = threadIdx.x;
    const int rb = blockIdx.x * 32;
    const int w = tid >> 6, l = tid & 63, lr = l & 15, g = l >> 4;
    float s0 = scores[0], s1 = scores[1], s2 = scores[2];
    for (int it = 0; it < 4; ++it) {
        int i = tid + it * 1024;
        int r = i >> 7, kq = i & 127;
        const float* hp = hid + (size_t)(rb + r) * 1536 + kq * 4;
        float4 x0 = *(const float4*)(hp);
        float4 x1 = *(const float4*)(hp + 512);
        float4 x2 = *(const float4*)(hp + 1024);
        bf16* d = Al + r * 520 + kq * 4;
        d[0] = (bf16)(x0.x * s0 + x1.x * s1 + x2.x * s2);
        d[1] = (bf16)(x0.y * s0 + x1.y * s1 + x2.y * s2);
        d[2] = (bf16)(x0.z * s0 + x1.z * s1 + x2.z * s2);
        d[3] = (bf16)(x0.w * s0 + x1.w * s1 + x2.w * s2);
    }
    __syncthreads();
    int c = w * 16 + lr;
    bf16x8 wf[16];
#pragma unroll
    for (int ks = 0; ks < 16; ++ks)
        wf[ks] = *(const bf16x8*)(out_WT + (size_t)c * 512 + ks * 32 + g * 8);
    float biav = out_b[c];
    for (int rt = 0; rt < 2; ++rt) {
        f32x4 acc = {};
#pragma unroll
        for (int ks = 0; ks < 16; ++ks) {
            bf16x8 aF = *(const bf16x8*)(Al + (rt * 16 + lr) * 520 + ks * 32 + g * 8);
            acc = MFMA16(aF, wf[ks], acc);
        }
#pragma unroll
        for (int i2 = 0; i2 < 4; ++i2)
            out[(size_t)(rb + rt * 16 + g * 4 + i2) * 256 + c] = acc[i2] + biav;
    }
}

// ---------------------------------------------------------------------------
extern "C" void kernel_launch(void* const* d_in, const int* in_sizes, int n_in,
                              void* d_out, int out_size, void* d_ws, size_t ws_size,
                              hipStream_t stream) {
    const int* tokens = (const int*)d_in[0];
    const int* etok = (const int*)d_in[1];
    const float* node_emb = (const float*)d_in[2];
    const float* edge_emb = (const float*)d_in[3];
    const float* scale_W = (const float*)d_in[4];
    const float* scale_b = (const float*)d_in[5];
    const float* attn_W = (const float*)d_in[6];
    const float* attn_b = (const float*)d_in[7];
    const float* ictx = (const float*)d_in[8];
    const float* inter_W = (const float*)d_in[9];
    const float* inter_b = (const float*)d_in[10];
    const float* ictx2 = (const float*)d_in[11];
    const float* out_W = (const float*)d_in[12];
    const float* out_b = (const float*)d_in[13];
    float* out = (float*)d_out;
    char* ws = (char*)d_ws;

    // ws layout (bytes) — scanned buffer eliminated (~39.6 MB total)
    size_t off = 0;
    bf16* scale_WT = (bf16*)(ws + off); off += 256 * 256 * 2;            // 131072
    bf16* WtopT = (bf16*)(ws + off);    off += 512 * 256 * 2;            // 262144
    bf16* WbotT = (bf16*)(ws + off);    off += 512 * 256 * 2;            // 262144
    bf16* inter_WT = (bf16*)(ws + off); off += 512 * 512 * 2;            // 524288
    bf16* out_WT = (bf16*)(ws + off);   off += 512 * 256 * 2;            // 262144
    float* ce = (float*)(ws + off);     off += 16 * 128 * 4;             // 8192
    float* se = (float*)(ws + off);     off += 16 * 128 * 4;             // 8192
    float* S = (float*)(ws + off);      off += 3 * 512 * 4;              // 6144
    float* scores = (float*)(ws + off); off += 256;
    bf16* scaled_emb = (bf16*)(ws + off); off += (size_t)VN * 256 * 2;   // 25.6 MB
    float* hid = (float*)(ws + off);    off += (size_t)BB * 3 * 512 * 4; // 12.6 MB
    if (ws_size < off) return;  // insufficient scratch -> fail loudly (zeros)

    const int lds_k1 = 64 * 264 * 2;   // 33792
    const int lds_B = 78592;           // Als + h0l + lg2
    const int lds_k4 = 32 * 520 * 2;   // 33280
    (void)hipFuncSetAttribute((const void*)attn_kernel,
                              hipFuncAttributeMaxDynamicSharedMemorySize, lds_B);

    prep_kernel<<<1024, 256, 0, stream>>>(scale_W, attn_W, inter_W, out_W, edge_emb,
                                          scale_WT, WtopT, WbotT, inter_WT, out_WT, ce, se, S);
    emb_gemm_kernel<<<(VN + 63) / 64, 512, lds_k1, stream>>>(node_emb, scale_WT, scale_b,
                                                             scaled_emb);
    attn_kernel<<<3 * 512, 512, lds_B, stream>>>(tokens, etok, scaled_emb, WtopT, WbotT,
                                                 attn_b, ictx, ce, se, hid);
    inter_kernel<<<dim3(BB / 32, MM), 1024, lds_k4, stream>>>(hid, inter_WT, inter_b, S);
    scores_kernel<<<1, 512, 0, stream>>>(S, ictx2, scores);
    out_kernel<<<BB / 32, 1024, lds_k4, stream>>>(hid, scores, out_WT, out_b, out);
}